// Round 4
// baseline (53259.100 us; speedup 1.0000x reference)
//
#include <hip/hip_runtime.h>
#include <hip/hip_cooperative_groups.h>

namespace cg = cooperative_groups;

#define NTHREADS 1024
#define BT 16   // batch tile per workgroup group

constexpr int Bsz = 256, Tst = 128, HID = 1440;
constexpr int ORN = 384, PN = 112, LN = 64, KC = 864, MB = 16, OBS = 64;

struct Params {
  const float *obs, *h, *in_orn_w, *in_orn_b, *W_oto, *W_lto, *W_otp, *W_ltp, *W_ptp,
              *W_otl, *W_ptl, *W_ltl, *W_ktk, *W_mtk, *W_ptk, *W_ktm,
              *b_orn, *b_pn, *b_ln, *b_kc, *b_mbon, *readout_w, *readout_b;
  float *orn0, *orn1, *pn0, *pn1, *ln0, *ln1, *kc0, *kc1, *mbon, *y, *h2;
  int *bar;
};

// ---- ILP-4 dot (plain cached loads: state/weights XCD-L2-resident by construction) ----
template <int K>
__device__ __forceinline__ float dot4(const float* __restrict__ w, const float* __restrict__ a) {
  const float4* w4 = (const float4*)w;
  const float4* a4 = (const float4*)a;
  float x0 = 0.f, x1 = 0.f, x2 = 0.f, x3 = 0.f;
#pragma unroll 4
  for (int i = 0; i < K / 4; ++i) {
    float4 wv = w4[i], av = a4[i];
    x0 = fmaf(wv.x, av.x, x0); x1 = fmaf(wv.y, av.y, x1);
    x2 = fmaf(wv.z, av.z, x2); x3 = fmaf(wv.w, av.w, x3);
  }
  return (x0 + x1) + (x2 + x3);
}

// ---- dual-output dot from LDS ----
template <int K>
__device__ __forceinline__ void ddot(const float* __restrict__ w0, const float* __restrict__ w1,
                                     const float* __restrict__ a, float& r0, float& r1) {
  const float4* W0 = (const float4*)w0;
  const float4* W1 = (const float4*)w1;
  const float4* A  = (const float4*)a;
  float x0=0,x1=0,x2=0,x3=0, y0=0,y1=0,y2=0,y3=0;
#pragma unroll 4
  for (int i = 0; i < K / 4; ++i) {
    float4 av = A[i], u = W0[i], v = W1[i];
    x0 = fmaf(u.x, av.x, x0); x1 = fmaf(u.y, av.y, x1);
    x2 = fmaf(u.z, av.z, x2); x3 = fmaf(u.w, av.w, x3);
    y0 = fmaf(v.x, av.x, y0); y1 = fmaf(v.y, av.y, y1);
    y2 = fmaf(v.z, av.z, y2); y3 = fmaf(v.w, av.w, y3);
  }
  r0 += (x0 + x1) + (x2 + x3);
  r1 += (y0 + y1) + (y2 + y3);
}

// ---- stage a [BT x width] state segment into LDS (plain cached float4 loads) ----
__device__ __forceinline__ void load_seg(float* dst, int stride, int off,
                                         const float* g, int width, int b0, int tid) {
  int w4 = width >> 2;
  const float4* g4 = (const float4*)(g + (size_t)b0 * width);
  for (int idx = tid; idx < BT * w4; idx += NTHREADS) {
    int b = idx / w4, k = idx - b * w4;
    *(float4*)(dst + b * stride + off + 4 * k) = g4[(size_t)b * w4 + k];
  }
}

// ---- 16-WG barrier (HW-validated in round 2: grid=256, 1 block/CU, bg = wg & 15,
//      stride-16 members all on XCD bg&7 under round-robin dispatch).
//      Flags: relaxed agent atomics (LLC). Data: stays in the XCD L2.
//      Release: vmcnt(0). Acquire: L1-only invalidate; L2 is never flushed. ----
__device__ __forceinline__ void bar_sync(int* cnt, int* gen, int& lg, int tid) {
  __syncthreads();
  if (tid == 0) {
    int target = ++lg;
    asm volatile("s_waitcnt vmcnt(0)" ::: "memory");   // our stores visible in L2
    int old = __hip_atomic_fetch_add(cnt, 1, __ATOMIC_RELAXED, __HIP_MEMORY_SCOPE_AGENT);
    if (old == 15) {
      __hip_atomic_store(cnt, 0, __ATOMIC_RELAXED, __HIP_MEMORY_SCOPE_AGENT);
      asm volatile("s_waitcnt vmcnt(0)" ::: "memory");
      __hip_atomic_fetch_add(gen, 1, __ATOMIC_RELAXED, __HIP_MEMORY_SCOPE_AGENT);
    } else {
      while (__hip_atomic_load(gen, __ATOMIC_RELAXED, __HIP_MEMORY_SCOPE_AGENT) < target)
        __builtin_amdgcn_s_sleep(1);
    }
    asm volatile("buffer_inv sc0\n\ts_waitcnt vmcnt(0)" ::: "memory");  // L1-only inv
  }
  __syncthreads();
}

__global__ void __launch_bounds__(NTHREADS, 4)
conn_kernel(Params P) {
  cg::grid_group grid = cg::this_grid();
  // 16*996*4 + 16*24*4 = 65280 B <= 64 KiB static LDS limit. 1 block/CU, 16 waves/CU.
  __shared__ float act[BT * 996];
  __shared__ float xs[BT * 24];
  const int tid = threadIdx.x;
  const int wg = blockIdx.x;
  const int bg = wg & 15, ng = wg >> 4, b0 = bg * BT;   // validated mapping (round 2)
  int* cnt = P.bar + bg * 64;
  int* gen = P.bar + bg * 64 + 16;
  int lg = 0;

  // ---- init: scatter h into parity-1 state buffers; init this bg's barrier ----
  if (ng == 0) {
    if (tid == 0) { *cnt = 0; *gen = 0; }
    for (int idx = tid; idx < BT * HID; idx += NTHREADS) {
      int b = idx / HID, pos = idx - b * HID, gb = b0 + b;
      float v = P.h[(size_t)gb * HID + pos];
      if      (pos < 384)  P.orn1[(size_t)gb * ORN + pos] = v;
      else if (pos < 496)  P.pn1[gb * PN + (pos - 384)] = v;
      else if (pos < 560)  P.ln1[gb * LN + (pos - 496)] = v;
      else if (pos < 1424) P.kc1[(size_t)gb * KC + (pos - 560)] = v;
      else                 P.mbon[gb * MB + (pos - 1424)] = v;
    }
  }
  grid.sync();  // once: publishes init + barrier zeros

  for (int s = 0; s < Tst * 4; ++s) {
    const int t = s >> 2, i = s & 3, p = s & 1;
    float* ornN = p ? P.orn1 : P.orn0;  const float* ornO = p ? P.orn0 : P.orn1;
    float* pnN  = p ? P.pn1  : P.pn0;   const float* pnO  = p ? P.pn0  : P.pn1;
    float* lnN  = p ? P.ln1  : P.ln0;   const float* lnO  = p ? P.ln0  : P.ln1;
    float* kcN  = p ? P.kc1  : P.kc0;   const float* kcO  = p ? P.kc0  : P.kc1;

    // ==== Stage A: orn split-K x4 (0-767) + mbon_{s-1} x8 (768-895) + x_t (896-1023) ====
    load_seg(act, 452, 0,   ornO, ORN, b0, tid);
    load_seg(act, 452, 384, lnO,  LN,  b0, tid);
    if (i == 0 && tid >= 896) {  // x_t slice, once per timestep, overlaps staging
      for (int o = tid - 896; o < BT * 24; o += 128) {
        int b = o / 24, jl = o - b * 24, j = ng * 24 + jl;
        xs[b * 24 + jl] = P.in_orn_b[j]
          + dot4<OBS>(P.in_orn_w + (size_t)j * OBS,
                      P.obs + ((size_t)(b0 + b) * Tst + t) * OBS);
      }
    }
    __syncthreads();
    if (tid < 768) {
      int b = tid & 15, q = (tid >> 4) & 3, jp = tid >> 6;  // partners tid^16, tid^32 (in-wave)
      int j0 = ng * 24 + jp * 2, j1 = j0 + 1;
      float r0 = 0.f, r1 = 0.f;
      if (q == 0) {
        r0 = xs[b * 24 + jp * 2]     + P.b_orn[j0];
        r1 = xs[b * 24 + jp * 2 + 1] + P.b_orn[j1];
        ddot<112>(P.W_oto + (size_t)j0 * ORN, P.W_oto + (size_t)j1 * ORN, act + b * 452, r0, r1);
      } else if (q == 1) {
        ddot<112>(P.W_oto + (size_t)j0 * ORN + 112, P.W_oto + (size_t)j1 * ORN + 112,
                  act + b * 452 + 112, r0, r1);
      } else if (q == 2) {
        ddot<112>(P.W_oto + (size_t)j0 * ORN + 224, P.W_oto + (size_t)j1 * ORN + 224,
                  act + b * 452 + 224, r0, r1);
      } else {
        ddot<48>(P.W_oto + (size_t)j0 * ORN + 336, P.W_oto + (size_t)j1 * ORN + 336,
                 act + b * 452 + 336, r0, r1);
        ddot<64>(P.W_lto + (size_t)j0 * LN, P.W_lto + (size_t)j1 * LN,
                 act + b * 452 + 384, r0, r1);
      }
      r0 += __shfl_xor(r0, 16);  r0 += __shfl_xor(r0, 32);
      r1 += __shfl_xor(r1, 16);  r1 += __shfl_xor(r1, 32);
      if (q == 0)
        *(float2*)&ornN[(size_t)(b0 + b) * ORN + j0] = make_float2(tanhf(r0), tanhf(r1));
    } else if (tid < 896) {
      if (s > 0) {  // mbon_{s-1}: 128 threads, 8-way K-split of 864
        int idx = tid - 768, b = idx >> 3, ks = idx & 7;
        float part = dot4<108>(P.W_ktm + (size_t)ng * KC + ks * 108,
                               kcO + (size_t)(b0 + b) * KC + ks * 108);
        part += __shfl_xor(part, 1);
        part += __shfl_xor(part, 2);
        part += __shfl_xor(part, 4);
        if (ks == 0)
          P.mbon[(b0 + b) * MB + ng] = tanhf(part + P.b_mbon[ng]);
      }
    }
    bar_sync(cnt, gen, lg, tid);

    // ==== Stage B: pn split-K x4 (0-447) + y_{t-1} (448-1023, i==0) ====
    load_seg(act, 564, 0,   ornN, ORN, b0, tid);
    load_seg(act, 564, 384, lnO,  LN,  b0, tid);
    load_seg(act, 564, 448, pnO,  PN,  b0, tid);
    __syncthreads();
    if (tid < 448) {
      int b = tid & 15, q = (tid >> 4) & 3, jl = tid >> 6;  // partners tid^16, tid^32 (in-wave)
      int j = ng * 7 + jl;
      const float* A = act + b * 564;
      float acc = 0.f;
      if      (q == 0) acc = P.b_pn[j] + dot4<192>(P.W_otp + (size_t)j * ORN,       A);
      else if (q == 1) acc = dot4<192>(P.W_otp + (size_t)j * ORN + 192, A + 192);
      else if (q == 2) acc = dot4<64>(P.W_ltp + (size_t)j * LN, A + 384)
                           + dot4<48>(P.W_ptp + (size_t)j * PN, A + 448);
      else             acc = dot4<64>(P.W_ptp + (size_t)j * PN + 48, A + 496);
      acc += __shfl_xor(acc, 16);
      acc += __shfl_xor(acc, 32);
      if (q == 0)
        pnN[(size_t)(b0 + b) * PN + j] = tanhf(acc);
    } else if (i == 0 && s > 0) {  // y_{t-1}: rank-16 readout from mbon_{t-1,final}
      for (int o = tid - 448; o < BT * 90; o += 576) {
        int b = o / 90, jl = o - b * 90, j = ng * 90 + jl;
        float yv = P.readout_b[j]
          + dot4<MB>(P.readout_w + (size_t)j * MB, P.mbon + (size_t)(b0 + b) * MB);
        P.y[((size_t)(b0 + b) * Tst + (t - 1)) * HID + j] = yv;
      }
    }
    bar_sync(cnt, gen, lg, tid);

    // ==== Stage C: kc split-K x2 (0-863, LDS) + ln split-K x2 (896-1023) ====
    load_seg(act, 996, 0,   kcO,    KC, b0, tid);
    load_seg(act, 996, 864, pnN,    PN, b0, tid);
    load_seg(act, 996, 976, P.mbon, MB, b0, tid);
    __syncthreads();
    if (tid < 864) {
      int b = tid & 15, half = (tid >> 4) & 1, jp = tid >> 5;   // partner tid^16 (in-wave)
      int j0 = ng * 54 + jp * 2, j1 = j0 + 1;
      float r0 = 0.f, r1 = 0.f;
      if (half == 0) {
        r0 = P.b_kc[j0]; r1 = P.b_kc[j1];
        ddot<432>(P.W_ktk + (size_t)j0 * KC, P.W_ktk + (size_t)j1 * KC, act + b * 996, r0, r1);
        ddot<PN> (P.W_ptk + (size_t)j0 * PN, P.W_ptk + (size_t)j1 * PN, act + b * 996 + 864, r0, r1);
      } else {
        ddot<432>(P.W_ktk + (size_t)j0 * KC + 432, P.W_ktk + (size_t)j1 * KC + 432,
                  act + b * 996 + 432, r0, r1);
        ddot<MB> (P.W_mtk + (size_t)j0 * MB, P.W_mtk + (size_t)j1 * MB, act + b * 996 + 976, r0, r1);
      }
      r0 += __shfl_xor(r0, 16);
      r1 += __shfl_xor(r1, 16);
      if (half == 0)
        *(float2*)&kcN[(size_t)(b0 + b) * KC + j0] = make_float2(tanhf(r0), tanhf(r1));
    } else if (tid >= 896) {
      int l = tid - 896, b = l & 15, half = (l >> 4) & 1, jl = l >> 5;  // partner l^16 (in-wave)
      int j = ng * 4 + jl;
      const float* ornRow = ornN + (size_t)(b0 + b) * ORN;
      float acc = 0.f;
      if (half == 0) {
        acc = P.b_ln[j] + dot4<288>(P.W_otl + (size_t)j * ORN, ornRow);
      } else {
        acc = dot4<96>(P.W_otl + (size_t)j * ORN + 288, ornRow + 288)
            + dot4<PN>(P.W_ptl + (size_t)j * PN, act + b * 996 + 864)   // pn from staged LDS
            + dot4<LN>(P.W_ltl + (size_t)j * LN, lnO + (size_t)(b0 + b) * LN);
      }
      acc += __shfl_xor(acc, 16);
      if (half == 0)
        lnN[(size_t)(b0 + b) * LN + j] = tanhf(acc);
    }
    bar_sync(cnt, gen, lg, tid);
  }

  // ================= tail: mbon_{511}, y_{127}, h2 =================
  if (tid < 128) {
    int b = tid >> 3, ks = tid & 7;
    float part = dot4<108>(P.W_ktm + (size_t)ng * KC + ks * 108,
                           P.kc1 + (size_t)(b0 + b) * KC + ks * 108);
    part += __shfl_xor(part, 1);
    part += __shfl_xor(part, 2);
    part += __shfl_xor(part, 4);
    if (ks == 0)
      P.mbon[(b0 + b) * MB + ng] = tanhf(part + P.b_mbon[ng]);
  }
  bar_sync(cnt, gen, lg, tid);
  for (int o = tid; o < BT * 90; o += NTHREADS) {
    int b = o / 90, jl = o - b * 90, j = ng * 90 + jl;
    float acc = P.readout_b[j]
      + dot4<MB>(P.readout_w + (size_t)j * MB, P.mbon + (size_t)(b0 + b) * MB);
    P.y[((size_t)(b0 + b) * Tst + (Tst - 1)) * HID + j] = acc;
  }
  for (int idx = tid; idx < BT * 90; idx += NTHREADS) {
    int b = idx / 90, pos = idx - b * 90, gb = b0 + b;
    float v; int hp;
    if      (pos < 24) { v = P.orn1[(size_t)gb * ORN + ng * 24 + pos]; hp = ng * 24 + pos; }
    else if (pos < 31) { int l = pos - 24; v = P.pn1[gb * PN + ng * 7 + l]; hp = 384 + ng * 7 + l; }
    else if (pos < 35) { int l = pos - 31; v = P.ln1[gb * LN + ng * 4 + l]; hp = 496 + ng * 4 + l; }
    else if (pos < 89) { int l = pos - 35; v = P.kc1[(size_t)gb * KC + ng * 54 + l]; hp = 560 + ng * 54 + l; }
    else               { v = P.mbon[gb * MB + ng]; hp = 1424 + ng; }
    P.h2[(size_t)gb * HID + hp] = v;
  }
}

extern "C" void kernel_launch(void* const* d_in, const int* in_sizes, int n_in,
                              void* d_out, int out_size, void* d_ws, size_t ws_size,
                              hipStream_t stream) {
  Params P;
  P.obs       = (const float*)d_in[0];
  P.h         = (const float*)d_in[1];
  P.in_orn_w  = (const float*)d_in[2];
  P.in_orn_b  = (const float*)d_in[3];
  P.W_oto     = (const float*)d_in[4];
  P.W_lto     = (const float*)d_in[5];
  P.W_otp     = (const float*)d_in[6];
  P.W_ltp     = (const float*)d_in[7];
  P.W_ptp     = (const float*)d_in[8];
  P.W_otl     = (const float*)d_in[9];
  P.W_ptl     = (const float*)d_in[10];
  P.W_ltl     = (const float*)d_in[11];
  P.W_ktk     = (const float*)d_in[12];
  P.W_mtk     = (const float*)d_in[13];
  P.W_ptk     = (const float*)d_in[14];
  P.W_ktm     = (const float*)d_in[15];
  P.b_orn     = (const float*)d_in[16];
  P.b_pn      = (const float*)d_in[17];
  P.b_ln      = (const float*)d_in[18];
  P.b_kc      = (const float*)d_in[19];
  P.b_mbon    = (const float*)d_in[20];
  P.readout_w = (const float*)d_in[21];
  P.readout_b = (const float*)d_in[22];

  float* ws = (float*)d_ws;
  size_t off = 0;
  P.orn0 = ws + off; off += (size_t)Bsz * ORN;
  P.orn1 = ws + off; off += (size_t)Bsz * ORN;
  P.pn0  = ws + off; off += (size_t)Bsz * PN;
  P.pn1  = ws + off; off += (size_t)Bsz * PN;
  P.ln0  = ws + off; off += (size_t)Bsz * LN;
  P.ln1  = ws + off; off += (size_t)Bsz * LN;
  P.kc0  = ws + off; off += (size_t)Bsz * KC;
  P.kc1  = ws + off; off += (size_t)Bsz * KC;
  P.mbon = ws + off; off += (size_t)Bsz * MB;
  P.bar  = (int*)(ws + off); off += 16 * 64;  // 16 batch groups x 64 ints

  P.y  = (float*)d_out;
  P.h2 = (float*)d_out + (size_t)Bsz * Tst * HID;

  void* args[] = { &P };
  hipLaunchCooperativeKernel((void*)conn_kernel, dim3(256), dim3(NTHREADS), args, 0, stream);
}

// Round 5
// 34896.161 us; speedup vs baseline: 1.5262x; 1.5262x over previous
//
#include <hip/hip_runtime.h>
#include <hip/hip_cooperative_groups.h>

namespace cg = cooperative_groups;

#define NTHREADS 1024
#define BT 16   // batch tile per workgroup group

constexpr int Bsz = 256, Tst = 128, HID = 1440;
constexpr int ORN = 384, PN = 112, LN = 64, KC = 864, MB = 16, OBS = 64;

struct Params {
  const float *obs, *h, *in_orn_w, *in_orn_b, *W_oto, *W_lto, *W_otp, *W_ltp, *W_ptp,
              *W_otl, *W_ptl, *W_ltl, *W_ktk, *W_mtk, *W_ptk, *W_ktm,
              *b_orn, *b_pn, *b_ln, *b_kc, *b_mbon, *readout_w, *readout_b;
  float *orn0, *orn1, *pn0, *pn1, *ln0, *ln1, *kc0, *kc1, *mbon, *y, *h2;
  float *Wp_orn, *Wp_pn;   // packed contiguous-K weights (built at init)
  int *bar;
};

// ---- ILP-4 dot (plain cached loads: state/weights XCD-L2-resident by construction) ----
template <int K>
__device__ __forceinline__ float dot4(const float* __restrict__ w, const float* __restrict__ a) {
  const float4* w4 = (const float4*)w;
  const float4* a4 = (const float4*)a;
  float x0 = 0.f, x1 = 0.f, x2 = 0.f, x3 = 0.f;
#pragma unroll 4
  for (int i = 0; i < K / 4; ++i) {
    float4 wv = w4[i], av = a4[i];
    x0 = fmaf(wv.x, av.x, x0); x1 = fmaf(wv.y, av.y, x1);
    x2 = fmaf(wv.z, av.z, x2); x3 = fmaf(wv.w, av.w, x3);
  }
  return (x0 + x1) + (x2 + x3);
}

// ---- stage a [BT x width] state segment into LDS (plain cached float4 loads) ----
__device__ __forceinline__ void load_seg(float* dst, int stride, int off,
                                         const float* g, int width, int b0, int tid) {
  int w4 = width >> 2;
  const float4* g4 = (const float4*)(g + (size_t)b0 * width);
  for (int idx = tid; idx < BT * w4; idx += NTHREADS) {
    int b = idx / w4, k = idx - b * w4;
    *(float4*)(dst + b * stride + off + 4 * k) = g4[(size_t)b * w4 + k];
  }
}

// ---- 16-WG barrier (HW-validated in round 2: grid=256, 1 block/CU, bg = wg & 15,
//      stride-16 members all on XCD bg&7 under round-robin dispatch).
//      Flags: relaxed agent atomics (LLC). Data: stays in the XCD L2.
//      Release: vmcnt(0). Acquire: L1-only invalidate; L2 is never flushed. ----
__device__ __forceinline__ void bar_sync(int* cnt, int* gen, int& lg, int tid) {
  __syncthreads();
  if (tid == 0) {
    int target = ++lg;
    asm volatile("s_waitcnt vmcnt(0)" ::: "memory");   // our stores visible in L2
    int old = __hip_atomic_fetch_add(cnt, 1, __ATOMIC_RELAXED, __HIP_MEMORY_SCOPE_AGENT);
    if (old == 15) {
      __hip_atomic_store(cnt, 0, __ATOMIC_RELAXED, __HIP_MEMORY_SCOPE_AGENT);
      asm volatile("s_waitcnt vmcnt(0)" ::: "memory");
      __hip_atomic_fetch_add(gen, 1, __ATOMIC_RELAXED, __HIP_MEMORY_SCOPE_AGENT);
    } else {
      while (__hip_atomic_load(gen, __ATOMIC_RELAXED, __HIP_MEMORY_SCOPE_AGENT) < target)
        __builtin_amdgcn_s_sleep(1);
    }
    asm volatile("buffer_inv sc0\n\ts_waitcnt vmcnt(0)" ::: "memory");  // L1-only inv
  }
  __syncthreads();
}

__global__ void __launch_bounds__(NTHREADS, 4)
conn_kernel(Params P) {
  cg::grid_group grid = cg::this_grid();
  // 16*996*4 + 16*24*4 = 65280 B <= 64 KiB static LDS limit. 1 block/CU, 16 waves/CU.
  __shared__ float act[BT * 996];
  __shared__ float xs[BT * 24];
  const int tid = threadIdx.x;
  const int wg = blockIdx.x;
  const int bg = wg & 15, ng = wg >> 4, b0 = bg * BT;   // validated mapping (round 2)
  int* cnt = P.bar + bg * 64;
  int* gen = P.bar + bg * 64 + 16;
  int lg = 0;

  // ---- init 1: pack weights into contiguous-K rows (agent stores -> LLC-coherent,
  //      readable by all XCDs' plain loads after grid.sync). Done once, all WGs. ----
  for (int idx = wg * NTHREADS + tid; idx < 384 * 448; idx += 256 * NTHREADS) {
    int r = idx / 448, c = idx - r * 448;
    float v = (c < 384) ? P.W_oto[(size_t)r * 384 + c] : P.W_lto[(size_t)r * 64 + (c - 384)];
    __hip_atomic_store((unsigned*)&P.Wp_orn[idx], __float_as_uint(v),
                       __ATOMIC_RELAXED, __HIP_MEMORY_SCOPE_AGENT);
  }
  for (int idx = wg * NTHREADS + tid; idx < 112 * 560; idx += 256 * NTHREADS) {
    int r = idx / 560, c = idx - r * 560;
    float v = (c < 384) ? P.W_otp[(size_t)r * 384 + c]
            : (c < 448) ? P.W_ltp[(size_t)r * 64 + (c - 384)]
                        : P.W_ptp[(size_t)r * 112 + (c - 448)];
    __hip_atomic_store((unsigned*)&P.Wp_pn[idx], __float_as_uint(v),
                       __ATOMIC_RELAXED, __HIP_MEMORY_SCOPE_AGENT);
  }

  // ---- init 2: scatter h into parity-1 state buffers; init this bg's barrier ----
  if (ng == 0) {
    if (tid == 0) { *cnt = 0; *gen = 0; }
    for (int idx = tid; idx < BT * HID; idx += NTHREADS) {
      int b = idx / HID, pos = idx - b * HID, gb = b0 + b;
      float v = P.h[(size_t)gb * HID + pos];
      if      (pos < 384)  P.orn1[(size_t)gb * ORN + pos] = v;
      else if (pos < 496)  P.pn1[gb * PN + (pos - 384)] = v;
      else if (pos < 560)  P.ln1[gb * LN + (pos - 496)] = v;
      else if (pos < 1424) P.kc1[(size_t)gb * KC + (pos - 560)] = v;
      else                 P.mbon[gb * MB + (pos - 1424)] = v;
    }
  }
  grid.sync();  // once: publishes init + packed weights + barrier zeros

  for (int s = 0; s < Tst * 4; ++s) {
    const int t = s >> 2, i = s & 3, p = s & 1;
    float* ornN = p ? P.orn1 : P.orn0;  const float* ornO = p ? P.orn0 : P.orn1;
    float* pnN  = p ? P.pn1  : P.pn0;   const float* pnO  = p ? P.pn0  : P.pn1;
    float* lnN  = p ? P.ln1  : P.ln0;   const float* lnO  = p ? P.ln0  : P.ln1;
    float* kcN  = p ? P.kc1  : P.kc0;   const float* kcO  = p ? P.kc0  : P.kc1;

    // ==== Stage A: orn K-split x2 BRANCHLESS (0-767) + mbon_{s-1} (768-895) + x_t ====
    load_seg(act, 452, 0,   ornO, ORN, b0, tid);
    load_seg(act, 452, 384, lnO,  LN,  b0, tid);
    if (i == 0 && tid >= 896) {  // x_t slice, once per timestep, overlaps staging
      for (int o = tid - 896; o < BT * 24; o += 128) {
        int b = o / 24, jl = o - b * 24, j = ng * 24 + jl;
        xs[b * 24 + jl] = P.in_orn_b[j]
          + dot4<OBS>(P.in_orn_w + (size_t)j * OBS,
                      P.obs + ((size_t)(b0 + b) * Tst + t) * OBS);
      }
    }
    __syncthreads();
    if (tid < 768) {  // 12 waves; ks is a pointer offset, SAME code path for all lanes
      int b = tid & 15, ks = (tid >> 4) & 1, j = tid >> 5;   // partner tid^16 (in-wave)
      int jg = ng * 24 + j;
      float r = dot4<224>(P.Wp_orn + (size_t)jg * 448 + ks * 224,
                          act + b * 452 + ks * 224);
      r += __shfl_xor(r, 16);
      if (ks == 0) {
        r += xs[b * 24 + j] + P.b_orn[jg];
        ornN[(size_t)(b0 + b) * ORN + jg] = tanhf(r);
      }
    } else if (tid < 896) {
      if (s > 0) {  // mbon_{s-1}: 128 thr, 8-way K-split via pointer offset (branchless)
        int idx = tid - 768, b = idx >> 3, ks = idx & 7;
        float part = dot4<108>(P.W_ktm + (size_t)ng * KC + ks * 108,
                               kcO + (size_t)(b0 + b) * KC + ks * 108);
        part += __shfl_xor(part, 1);
        part += __shfl_xor(part, 2);
        part += __shfl_xor(part, 4);
        if (ks == 0)
          P.mbon[(b0 + b) * MB + ng] = tanhf(part + P.b_mbon[ng]);
      }
    }
    bar_sync(cnt, gen, lg, tid);

    // ==== Stage B: pn K-split x4 BRANCHLESS (0-447) + y_{t-1} (512-1023, i==0) ====
    load_seg(act, 564, 0,   ornN, ORN, b0, tid);
    load_seg(act, 564, 384, lnO,  LN,  b0, tid);
    load_seg(act, 564, 448, pnO,  PN,  b0, tid);
    __syncthreads();
    if (tid < 448) {  // 7 waves: wave = j; lanes = 16 b x 4 ks, single code path
      int b = tid & 15, ks = (tid >> 4) & 3, j = tid >> 6;   // partners tid^16, tid^32
      int jg = ng * 7 + j;
      float r = dot4<140>(P.Wp_pn + (size_t)jg * 560 + ks * 140,
                          act + b * 564 + ks * 140);
      r += __shfl_xor(r, 16);
      r += __shfl_xor(r, 32);
      if (ks == 0) {
        r += P.b_pn[jg];
        pnN[(size_t)(b0 + b) * PN + jg] = tanhf(r);
      }
    } else if (i == 0 && s > 0 && tid >= 512) {  // y_{t-1}: rank-16 readout from mbon
      for (int o = tid - 512; o < BT * 90; o += 512) {
        int b = o / 90, jl = o - b * 90, j = ng * 90 + jl;
        float yv = P.readout_b[j]
          + dot4<MB>(P.readout_w + (size_t)j * MB, P.mbon + (size_t)(b0 + b) * MB);
        P.y[((size_t)(b0 + b) * Tst + (t - 1)) * HID + j] = yv;
      }
    }
    bar_sync(cnt, gen, lg, tid);

    // ==== Stage C: kc one-output-per-thread (0-863, uniform) + ln one wave (896-959) ====
    load_seg(act, 996, 0,   kcO,    KC, b0, tid);
    load_seg(act, 996, 864, pnN,    PN, b0, tid);
    load_seg(act, 996, 976, P.mbon, MB, b0, tid);
    __syncthreads();
    if (tid < 864) {  // 13.5 waves, full-K dot, no split, no divergence
      int b = tid & 15, j = tid >> 4, jg = ng * 54 + j;
      const float* A = act + b * 996;
      float r = P.b_kc[jg]
        + dot4<KC>(P.W_ktk + (size_t)jg * KC, A)
        + dot4<PN>(P.W_ptk + (size_t)jg * PN, A + 864)
        + dot4<MB>(P.W_mtk + (size_t)jg * MB, A + 976);
      kcN[(size_t)(b0 + b) * KC + jg] = tanhf(r);
    } else if (tid >= 896 && tid < 960) {  // ln: exactly one wave, 64 outputs, full K
      int l = tid - 896, b = l & 15, j = l >> 4, jg = ng * 4 + j;
      float r = P.b_ln[jg]
        + dot4<ORN>(P.W_otl + (size_t)jg * ORN, ornN + (size_t)(b0 + b) * ORN)
        + dot4<PN> (P.W_ptl + (size_t)jg * PN,  act + b * 996 + 864)   // pn from LDS
        + dot4<LN> (P.W_ltl + (size_t)jg * LN,  lnO + (size_t)(b0 + b) * LN);
      lnN[(size_t)(b0 + b) * LN + jg] = tanhf(r);
    }
    bar_sync(cnt, gen, lg, tid);
  }

  // ================= tail: mbon_{511}, y_{127}, h2 =================
  if (tid < 128) {
    int b = tid >> 3, ks = tid & 7;
    float part = dot4<108>(P.W_ktm + (size_t)ng * KC + ks * 108,
                           P.kc1 + (size_t)(b0 + b) * KC + ks * 108);
    part += __shfl_xor(part, 1);
    part += __shfl_xor(part, 2);
    part += __shfl_xor(part, 4);
    if (ks == 0)
      P.mbon[(b0 + b) * MB + ng] = tanhf(part + P.b_mbon[ng]);
  }
  bar_sync(cnt, gen, lg, tid);
  for (int o = tid; o < BT * 90; o += NTHREADS) {
    int b = o / 90, jl = o - b * 90, j = ng * 90 + jl;
    float acc = P.readout_b[j]
      + dot4<MB>(P.readout_w + (size_t)j * MB, P.mbon + (size_t)(b0 + b) * MB);
    P.y[((size_t)(b0 + b) * Tst + (Tst - 1)) * HID + j] = acc;
  }
  for (int idx = tid; idx < BT * 90; idx += NTHREADS) {
    int b = idx / 90, pos = idx - b * 90, gb = b0 + b;
    float v; int hp;
    if      (pos < 24) { v = P.orn1[(size_t)gb * ORN + ng * 24 + pos]; hp = ng * 24 + pos; }
    else if (pos < 31) { int l = pos - 24; v = P.pn1[gb * PN + ng * 7 + l]; hp = 384 + ng * 7 + l; }
    else if (pos < 35) { int l = pos - 31; v = P.ln1[gb * LN + ng * 4 + l]; hp = 496 + ng * 4 + l; }
    else if (pos < 89) { int l = pos - 35; v = P.kc1[(size_t)gb * KC + ng * 54 + l]; hp = 560 + ng * 54 + l; }
    else               { v = P.mbon[gb * MB + ng]; hp = 1424 + ng; }
    P.h2[(size_t)gb * HID + hp] = v;
  }
}

extern "C" void kernel_launch(void* const* d_in, const int* in_sizes, int n_in,
                              void* d_out, int out_size, void* d_ws, size_t ws_size,
                              hipStream_t stream) {
  Params P;
  P.obs       = (const float*)d_in[0];
  P.h         = (const float*)d_in[1];
  P.in_orn_w  = (const float*)d_in[2];
  P.in_orn_b  = (const float*)d_in[3];
  P.W_oto     = (const float*)d_in[4];
  P.W_lto     = (const float*)d_in[5];
  P.W_otp     = (const float*)d_in[6];
  P.W_ltp     = (const float*)d_in[7];
  P.W_ptp     = (const float*)d_in[8];
  P.W_otl     = (const float*)d_in[9];
  P.W_ptl     = (const float*)d_in[10];
  P.W_ltl     = (const float*)d_in[11];
  P.W_ktk     = (const float*)d_in[12];
  P.W_mtk     = (const float*)d_in[13];
  P.W_ptk     = (const float*)d_in[14];
  P.W_ktm     = (const float*)d_in[15];
  P.b_orn     = (const float*)d_in[16];
  P.b_pn      = (const float*)d_in[17];
  P.b_ln      = (const float*)d_in[18];
  P.b_kc      = (const float*)d_in[19];
  P.b_mbon    = (const float*)d_in[20];
  P.readout_w = (const float*)d_in[21];
  P.readout_b = (const float*)d_in[22];

  float* ws = (float*)d_ws;
  size_t off = 0;
  P.orn0 = ws + off; off += (size_t)Bsz * ORN;
  P.orn1 = ws + off; off += (size_t)Bsz * ORN;
  P.pn0  = ws + off; off += (size_t)Bsz * PN;
  P.pn1  = ws + off; off += (size_t)Bsz * PN;
  P.ln0  = ws + off; off += (size_t)Bsz * LN;
  P.ln1  = ws + off; off += (size_t)Bsz * LN;
  P.kc0  = ws + off; off += (size_t)Bsz * KC;
  P.kc1  = ws + off; off += (size_t)Bsz * KC;
  P.mbon = ws + off; off += (size_t)Bsz * MB;
  P.bar  = (int*)(ws + off); off += 16 * 64;  // 16 batch groups x 64 ints
  P.Wp_orn = ws + off; off += (size_t)384 * 448;   // packed [W_oto|W_lto]
  P.Wp_pn  = ws + off; off += (size_t)112 * 560;   // packed [W_otp|W_ltp|W_ptp]

  P.y  = (float*)d_out;
  P.h2 = (float*)d_out + (size_t)Bsz * Tst * HID;

  void* args[] = { &P };
  hipLaunchCooperativeKernel((void*)conn_kernel, dim3(256), dim3(NTHREADS), args, 0, stream);
}

// Round 6
// 17599.667 us; speedup vs baseline: 3.0261x; 1.9828x over previous
//
#include <hip/hip_runtime.h>
#include <hip/hip_fp16.h>
#include <hip/hip_cooperative_groups.h>

namespace cg = cooperative_groups;

#define NTHREADS 1024
#define BT 16   // batch tile per workgroup group

constexpr int Bsz = 256, Tst = 128, HID = 1440;
constexpr int ORN = 384, PN = 112, LN = 64, KC = 864, MB = 16, OBS = 64;
// packed fp16 row widths (match LDS act layout exactly)
constexpr int WO = 448;   // orn: [W_oto 384 | W_lto 64]
constexpr int WP = 576;   // pn:  [W_otp 384 | W_ltp 64 | W_ptp 112 | zero 16]
constexpr int WK = 992;   // kc:  [W_ktk 864 | W_ptk 112 | W_mtk 16]
constexpr int WL = 560;   // ln:  [W_otl 384 | W_ptl 112 | W_ltl 64]

struct Params {
  const float *obs, *h, *in_orn_w, *in_orn_b, *W_oto, *W_lto, *W_otp, *W_ltp, *W_ptp,
              *W_otl, *W_ptl, *W_ltl, *W_ktk, *W_mtk, *W_ptk, *W_ktm,
              *b_orn, *b_pn, *b_ln, *b_kc, *b_mbon, *readout_w, *readout_b;
  float *orn0, *orn1, *pn0, *pn1, *ln0, *ln1, *kc0, *kc1, *mbon, *y, *h2;
  __half *Wp_orn, *Wp_pn, *Wp_kc, *Wp_ln, *Wh_ktm, *Wh_ro;  // packed fp16 (built at init)
  int *bar;
};

// ---- fp32 ILP-4 dot (x_t path only) ----
template <int K>
__device__ __forceinline__ float dot4(const float* __restrict__ w, const float* __restrict__ a) {
  const float4* w4 = (const float4*)w;
  const float4* a4 = (const float4*)a;
  float x0 = 0.f, x1 = 0.f, x2 = 0.f, x3 = 0.f;
#pragma unroll 4
  for (int i = 0; i < K / 4; ++i) {
    float4 wv = w4[i], av = a4[i];
    x0 = fmaf(wv.x, av.x, x0); x1 = fmaf(wv.y, av.y, x1);
    x2 = fmaf(wv.z, av.z, x2); x3 = fmaf(wv.w, av.w, x3);
  }
  return (x0 + x1) + (x2 + x3);
}

// ---- fp16-weight x fp32-act dot, ILP-4, 16B weight loads (8 halves/iter) ----
template <int K>  // K multiple of 8; w 16B-aligned
__device__ __forceinline__ float doth(const __half* __restrict__ w, const float* __restrict__ a) {
  const float4* w4 = (const float4*)w;   // 8 halves per float4
  const float4* a4 = (const float4*)a;
  float x0 = 0.f, x1 = 0.f, x2 = 0.f, x3 = 0.f;
#pragma unroll 4
  for (int i = 0; i < K / 8; ++i) {
    float4 wv = w4[i];
    float4 a0 = a4[2 * i], a1 = a4[2 * i + 1];
    __half2 h0 = __builtin_bit_cast(__half2, wv.x);
    __half2 h1 = __builtin_bit_cast(__half2, wv.y);
    __half2 h2 = __builtin_bit_cast(__half2, wv.z);
    __half2 h3 = __builtin_bit_cast(__half2, wv.w);
    x0 = fmaf(__low2float(h0), a0.x, x0); x1 = fmaf(__high2float(h0), a0.y, x1);
    x2 = fmaf(__low2float(h1), a0.z, x2); x3 = fmaf(__high2float(h1), a0.w, x3);
    x0 = fmaf(__low2float(h2), a1.x, x0); x1 = fmaf(__high2float(h2), a1.y, x1);
    x2 = fmaf(__low2float(h3), a1.z, x2); x3 = fmaf(__high2float(h3), a1.w, x3);
  }
  return (x0 + x1) + (x2 + x3);
}

// ---- stage a [BT x width] state segment into LDS (plain cached float4 loads) ----
__device__ __forceinline__ void load_seg(float* dst, int stride, int off,
                                         const float* g, int width, int b0, int tid) {
  int w4 = width >> 2;
  const float4* g4 = (const float4*)(g + (size_t)b0 * width);
  for (int idx = tid; idx < BT * w4; idx += NTHREADS) {
    int b = idx / w4, k = idx - b * w4;
    *(float4*)(dst + b * stride + off + 4 * k) = g4[(size_t)b * w4 + k];
  }
}

// ---- agent-scope (LLC) store of a packed half2 ----
__device__ __forceinline__ void st_h2(__half* p, float v0, float v1) {
  __half2 h = __floats2half2_rn(v0, v1);
  __hip_atomic_store((unsigned*)p, __builtin_bit_cast(unsigned, h),
                     __ATOMIC_RELAXED, __HIP_MEMORY_SCOPE_AGENT);
}

// ---- 16-WG barrier (HW-validated: grid=256, 1 block/CU, bg = wg & 15, stride-16
//      members all on XCD bg&7). Flags: relaxed agent atomics (LLC). Data: XCD L2.
//      Release: vmcnt(0). Acquire: L1-only invalidate; L2 is never flushed. ----
__device__ __forceinline__ void bar_sync(int* cnt, int* gen, int& lg, int tid) {
  __syncthreads();
  if (tid == 0) {
    int target = ++lg;
    asm volatile("s_waitcnt vmcnt(0)" ::: "memory");   // our stores visible in L2
    int old = __hip_atomic_fetch_add(cnt, 1, __ATOMIC_RELAXED, __HIP_MEMORY_SCOPE_AGENT);
    if (old == 15) {
      __hip_atomic_store(cnt, 0, __ATOMIC_RELAXED, __HIP_MEMORY_SCOPE_AGENT);
      asm volatile("s_waitcnt vmcnt(0)" ::: "memory");
      __hip_atomic_fetch_add(gen, 1, __ATOMIC_RELAXED, __HIP_MEMORY_SCOPE_AGENT);
    } else {
      while (__hip_atomic_load(gen, __ATOMIC_RELAXED, __HIP_MEMORY_SCOPE_AGENT) < target)
        __builtin_amdgcn_s_sleep(1);
    }
    asm volatile("buffer_inv sc0\n\ts_waitcnt vmcnt(0)" ::: "memory");  // L1-only inv
  }
  __syncthreads();
}

__global__ void __launch_bounds__(NTHREADS, 4)
conn_kernel(Params P) {
  cg::grid_group grid = cg::this_grid();
  // 16*996*4 + 16*24*4 = 65280 B <= 64 KiB. 1 block/CU, 16 waves/CU.
  __shared__ float act[BT * 996];
  __shared__ float xs[BT * 24];
  const int tid = threadIdx.x;
  const int wg = blockIdx.x;
  const int bg = wg & 15, ng = wg >> 4, b0 = bg * BT;   // validated mapping (round 2)
  int* cnt = P.bar + bg * 64;
  int* gen = P.bar + bg * 64 + 16;
  int lg = 0;

  // ---- init 1: pack ALL hot-loop weights to fp16 rows matching the act layout.
  //      Per-XCD L2 working set: 2.33 MB packed + ~0.4 MB fp32 state < 4 MiB -> resident.
  {
    const int gid = wg * NTHREADS + tid, gstr = 256 * NTHREADS;
    for (int idx = gid; idx < 384 * (WO / 2); idx += gstr) {   // orn rows
      int r = idx / (WO / 2), c = (idx - r * (WO / 2)) * 2;
      float v0, v1;
      if (c < 384) { v0 = P.W_oto[(size_t)r * 384 + c]; v1 = P.W_oto[(size_t)r * 384 + c + 1]; }
      else         { v0 = P.W_lto[(size_t)r * 64 + c - 384]; v1 = P.W_lto[(size_t)r * 64 + c - 383]; }
      st_h2(&P.Wp_orn[(size_t)r * WO + c], v0, v1);
    }
    for (int idx = gid; idx < 112 * (WP / 2); idx += gstr) {   // pn rows (+16 zero pad)
      int r = idx / (WP / 2), c = (idx - r * (WP / 2)) * 2;
      float v0, v1;
      if      (c < 384) { v0 = P.W_otp[(size_t)r * 384 + c];     v1 = P.W_otp[(size_t)r * 384 + c + 1]; }
      else if (c < 448) { v0 = P.W_ltp[(size_t)r * 64 + c - 384]; v1 = P.W_ltp[(size_t)r * 64 + c - 383]; }
      else if (c < 560) { v0 = P.W_ptp[(size_t)r * 112 + c - 448]; v1 = P.W_ptp[(size_t)r * 112 + c - 447]; }
      else              { v0 = 0.f; v1 = 0.f; }
      st_h2(&P.Wp_pn[(size_t)r * WP + c], v0, v1);
    }
    for (int idx = gid; idx < 864 * (WK / 2); idx += gstr) {   // kc rows
      int r = idx / (WK / 2), c = (idx - r * (WK / 2)) * 2;
      float v0, v1;
      if      (c < 864) { v0 = P.W_ktk[(size_t)r * 864 + c];      v1 = P.W_ktk[(size_t)r * 864 + c + 1]; }
      else if (c < 976) { v0 = P.W_ptk[(size_t)r * 112 + c - 864]; v1 = P.W_ptk[(size_t)r * 112 + c - 863]; }
      else              { v0 = P.W_mtk[(size_t)r * 16 + c - 976];  v1 = P.W_mtk[(size_t)r * 16 + c - 975]; }
      st_h2(&P.Wp_kc[(size_t)r * WK + c], v0, v1);
    }
    for (int idx = gid; idx < 64 * (WL / 2); idx += gstr) {    // ln rows
      int r = idx / (WL / 2), c = (idx - r * (WL / 2)) * 2;
      float v0, v1;
      if      (c < 384) { v0 = P.W_otl[(size_t)r * 384 + c];      v1 = P.W_otl[(size_t)r * 384 + c + 1]; }
      else if (c < 496) { v0 = P.W_ptl[(size_t)r * 112 + c - 384]; v1 = P.W_ptl[(size_t)r * 112 + c - 383]; }
      else              { v0 = P.W_ltl[(size_t)r * 64 + c - 496];  v1 = P.W_ltl[(size_t)r * 64 + c - 495]; }
      st_h2(&P.Wp_ln[(size_t)r * WL + c], v0, v1);
    }
    for (int idx = gid; idx < 16 * 432; idx += gstr) {         // W_ktm 16x864
      int c = idx * 2;
      st_h2(&P.Wh_ktm[c], P.W_ktm[c], P.W_ktm[c + 1]);
    }
    for (int idx = gid; idx < 1440 * 8; idx += gstr) {         // readout_w 1440x16
      int c = idx * 2;
      st_h2(&P.Wh_ro[c], P.readout_w[c], P.readout_w[c + 1]);
    }
  }

  // ---- init 2: scatter h into parity-1 state buffers; init this bg's barrier ----
  if (ng == 0) {
    if (tid == 0) { *cnt = 0; *gen = 0; }
    for (int idx = tid; idx < BT * HID; idx += NTHREADS) {
      int b = idx / HID, pos = idx - b * HID, gb = b0 + b;
      float v = P.h[(size_t)gb * HID + pos];
      if      (pos < 384)  P.orn1[(size_t)gb * ORN + pos] = v;
      else if (pos < 496)  P.pn1[gb * PN + (pos - 384)] = v;
      else if (pos < 560)  P.ln1[gb * LN + (pos - 496)] = v;
      else if (pos < 1424) P.kc1[(size_t)gb * KC + (pos - 560)] = v;
      else                 P.mbon[gb * MB + (pos - 1424)] = v;
    }
  }
  grid.sync();  // once: publishes packed weights + init + barrier zeros

  for (int s = 0; s < Tst * 4; ++s) {
    const int t = s >> 2, i = s & 3, p = s & 1;
    float* ornN = p ? P.orn1 : P.orn0;  const float* ornO = p ? P.orn0 : P.orn1;
    float* pnN  = p ? P.pn1  : P.pn0;   const float* pnO  = p ? P.pn0  : P.pn1;
    float* lnN  = p ? P.ln1  : P.ln0;   const float* lnO  = p ? P.ln0  : P.ln1;
    float* kcN  = p ? P.kc1  : P.kc0;   const float* kcO  = p ? P.kc0  : P.kc1;

    // ==== Stage A: orn full-K 1/thread (0-383, conflict-free broadcast)
    //      + mbon_{s-1} 4-way (448-511) + x_t (640-1023, i==0) ====
    load_seg(act, 996, 0,   ornO, ORN, b0, tid);
    load_seg(act, 996, 384, lnO,  LN,  b0, tid);
    if (i == 0 && tid >= 640) {  // x_t slice, once per timestep, overlaps staging
      for (int o = tid - 640; o < BT * 24; o += 384) {
        int b = o / 24, jl = o - b * 24, j = ng * 24 + jl;
        xs[b * 24 + jl] = P.in_orn_b[j]
          + dot4<OBS>(P.in_orn_w + (size_t)j * OBS,
                      P.obs + ((size_t)(b0 + b) * Tst + t) * OBS);
      }
    }
    __syncthreads();
    if (tid < 384) {  // 6 waves; one output/thread; j-groups broadcast same weight row
      int b = tid & 15, j = tid >> 4, jg = ng * 24 + j;
      float r = xs[b * 24 + j] + P.b_orn[jg]
              + doth<WO>(P.Wp_orn + (size_t)jg * WO, act + b * 996);
      ornN[(size_t)(b0 + b) * ORN + jg] = tanhf(r);
    } else if (tid >= 448 && tid < 512 && s > 0) {  // mbon: 64 thr, 4-way K-split (global kcO)
      int idx = tid - 448, b = idx >> 2, ks = idx & 3;
      float part = doth<216>(P.Wh_ktm + (size_t)ng * KC + ks * 216,
                             kcO + (size_t)(b0 + b) * KC + ks * 216);
      part += __shfl_xor(part, 1);
      part += __shfl_xor(part, 2);
      if (ks == 0)
        P.mbon[(b0 + b) * MB + ng] = tanhf(part + P.b_mbon[ng]);
    }
    bar_sync(cnt, gen, lg, tid);

    // ==== Stage B: pn 4-way K-split (0-447, branchless) + y_{t-1} (512-1023, i==0) ====
    load_seg(act, 996, 0,   ornN, ORN, b0, tid);
    load_seg(act, 996, 384, lnO,  LN,  b0, tid);
    load_seg(act, 996, 448, pnO,  PN,  b0, tid);
    for (int idx = tid; idx < BT * 4; idx += NTHREADS) {  // zero pad [560..576)
      int b = idx >> 2, k = idx & 3;
      *(float4*)(act + b * 996 + 560 + 4 * k) = make_float4(0.f, 0.f, 0.f, 0.f);
    }
    __syncthreads();
    if (tid < 448) {  // 7 waves; ks = pointer offset, single code path
      int b = tid & 15, ks = (tid >> 4) & 3, j = tid >> 6, jg = ng * 7 + j;
      float r = doth<144>(P.Wp_pn + (size_t)jg * WP + ks * 144,
                          act + b * 996 + ks * 144);
      r += __shfl_xor(r, 16);
      r += __shfl_xor(r, 32);
      if (ks == 0)
        pnN[(size_t)(b0 + b) * PN + jg] = tanhf(r + P.b_pn[jg]);
    } else if (i == 0 && s > 0 && tid >= 512) {  // y_{t-1}: rank-16 readout from mbon
      for (int o = tid - 512; o < BT * 90; o += 512) {
        int b = o / 90, jl = o - b * 90, j = ng * 90 + jl;
        float yv = P.readout_b[j]
          + doth<MB>(P.Wh_ro + (size_t)j * MB, P.mbon + (size_t)(b0 + b) * MB);
        P.y[((size_t)(b0 + b) * Tst + (t - 1)) * HID + j] = yv;
      }
    }
    bar_sync(cnt, gen, lg, tid);

    // ==== Stage C: kc full-K 1/thread (0-863, single 992-dot) + ln one wave (896-959) ====
    load_seg(act, 996, 0,   kcO,    KC, b0, tid);
    load_seg(act, 996, 864, pnN,    PN, b0, tid);
    load_seg(act, 996, 976, P.mbon, MB, b0, tid);
    __syncthreads();
    if (tid < 864) {  // 13.5 waves; packed row matches act layout -> one contiguous dot
      int b = tid & 15, j = tid >> 4, jg = ng * 54 + j;
      float r = P.b_kc[jg] + doth<WK>(P.Wp_kc + (size_t)jg * WK, act + b * 996);
      kcN[(size_t)(b0 + b) * KC + jg] = tanhf(r);
    } else if (tid >= 896 && tid < 960) {  // ln: one wave, full K
      int l = tid - 896, b = l & 15, j = l >> 4, jg = ng * 4 + j;
      const __half* row = P.Wp_ln + (size_t)jg * WL;
      float r = P.b_ln[jg]
        + doth<384>(row,       ornN + (size_t)(b0 + b) * ORN)
        + doth<112>(row + 384, act + b * 996 + 864)           // pn from staged LDS
        + doth<64> (row + 496, lnO + (size_t)(b0 + b) * LN);
      lnN[(size_t)(b0 + b) * LN + jg] = tanhf(r);
    }
    bar_sync(cnt, gen, lg, tid);
  }

  // ================= tail: mbon_{511}, y_{127}, h2 =================
  if (tid < 64) {
    int b = tid >> 2, ks = tid & 3;
    float part = doth<216>(P.Wh_ktm + (size_t)ng * KC + ks * 216,
                           P.kc1 + (size_t)(b0 + b) * KC + ks * 216);
    part += __shfl_xor(part, 1);
    part += __shfl_xor(part, 2);
    if (ks == 0)
      P.mbon[(b0 + b) * MB + ng] = tanhf(part + P.b_mbon[ng]);
  }
  bar_sync(cnt, gen, lg, tid);
  for (int o = tid; o < BT * 90; o += NTHREADS) {
    int b = o / 90, jl = o - b * 90, j = ng * 90 + jl;
    float acc = P.readout_b[j]
      + doth<MB>(P.Wh_ro + (size_t)j * MB, P.mbon + (size_t)(b0 + b) * MB);
    P.y[((size_t)(b0 + b) * Tst + (Tst - 1)) * HID + j] = acc;
  }
  for (int idx = tid; idx < BT * 90; idx += NTHREADS) {
    int b = idx / 90, pos = idx - b * 90, gb = b0 + b;
    float v; int hp;
    if      (pos < 24) { v = P.orn1[(size_t)gb * ORN + ng * 24 + pos]; hp = ng * 24 + pos; }
    else if (pos < 31) { int l = pos - 24; v = P.pn1[gb * PN + ng * 7 + l]; hp = 384 + ng * 7 + l; }
    else if (pos < 35) { int l = pos - 31; v = P.ln1[gb * LN + ng * 4 + l]; hp = 496 + ng * 4 + l; }
    else if (pos < 89) { int l = pos - 35; v = P.kc1[(size_t)gb * KC + ng * 54 + l]; hp = 560 + ng * 54 + l; }
    else               { v = P.mbon[gb * MB + ng]; hp = 1424 + ng; }
    P.h2[(size_t)gb * HID + hp] = v;
  }
}

extern "C" void kernel_launch(void* const* d_in, const int* in_sizes, int n_in,
                              void* d_out, int out_size, void* d_ws, size_t ws_size,
                              hipStream_t stream) {
  Params P;
  P.obs       = (const float*)d_in[0];
  P.h         = (const float*)d_in[1];
  P.in_orn_w  = (const float*)d_in[2];
  P.in_orn_b  = (const float*)d_in[3];
  P.W_oto     = (const float*)d_in[4];
  P.W_lto     = (const float*)d_in[5];
  P.W_otp     = (const float*)d_in[6];
  P.W_ltp     = (const float*)d_in[7];
  P.W_ptp     = (const float*)d_in[8];
  P.W_otl     = (const float*)d_in[9];
  P.W_ptl     = (const float*)d_in[10];
  P.W_ltl     = (const float*)d_in[11];
  P.W_ktk     = (const float*)d_in[12];
  P.W_mtk     = (const float*)d_in[13];
  P.W_ptk     = (const float*)d_in[14];
  P.W_ktm     = (const float*)d_in[15];
  P.b_orn     = (const float*)d_in[16];
  P.b_pn      = (const float*)d_in[17];
  P.b_ln      = (const float*)d_in[18];
  P.b_kc      = (const float*)d_in[19];
  P.b_mbon    = (const float*)d_in[20];
  P.readout_w = (const float*)d_in[21];
  P.readout_b = (const float*)d_in[22];

  float* ws = (float*)d_ws;
  size_t off = 0;
  P.orn0 = ws + off; off += (size_t)Bsz * ORN;
  P.orn1 = ws + off; off += (size_t)Bsz * ORN;
  P.pn0  = ws + off; off += (size_t)Bsz * PN;
  P.pn1  = ws + off; off += (size_t)Bsz * PN;
  P.ln0  = ws + off; off += (size_t)Bsz * LN;
  P.ln1  = ws + off; off += (size_t)Bsz * LN;
  P.kc0  = ws + off; off += (size_t)Bsz * KC;
  P.kc1  = ws + off; off += (size_t)Bsz * KC;
  P.mbon = ws + off; off += (size_t)Bsz * MB;
  P.bar  = (int*)(ws + off); off += 16 * 64;  // 16 batch groups x 64 ints
  // packed fp16 regions (sizes in floats = halves/2; all even)
  P.Wp_orn = (__half*)(ws + off); off += (size_t)384 * WO / 2;
  P.Wp_pn  = (__half*)(ws + off); off += (size_t)112 * WP / 2;
  P.Wp_kc  = (__half*)(ws + off); off += (size_t)864 * WK / 2;
  P.Wp_ln  = (__half*)(ws + off); off += (size_t)64  * WL / 2;
  P.Wh_ktm = (__half*)(ws + off); off += (size_t)16  * KC / 2;
  P.Wh_ro  = (__half*)(ws + off); off += (size_t)HID * MB / 2;

  P.y  = (float*)d_out;
  P.h2 = (float*)d_out + (size_t)Bsz * Tst * HID;

  void* args[] = { &P };
  hipLaunchCooperativeKernel((void*)conn_kernel, dim3(256), dim3(NTHREADS), args, 0, stream);
}

// Round 7
// 16817.648 us; speedup vs baseline: 3.1669x; 1.0465x over previous
//
#include <hip/hip_runtime.h>
#include <hip/hip_fp16.h>
#include <hip/hip_cooperative_groups.h>

namespace cg = cooperative_groups;

#define NTHREADS 1024
#define BT 16   // batch tile per workgroup group

constexpr int Bsz = 256, Tst = 128, HID = 1440;
constexpr int ORN = 384, PN = 112, LN = 64, KC = 864, MB = 16, OBS = 64;
// packed fp16 row widths (match LDS act layout exactly)
constexpr int WO = 448;   // orn: [W_oto 384 | W_lto 64]
constexpr int WP = 576;   // pn:  [W_otp 384 | W_ltp 64 | W_ptp 112 | zero 16]
constexpr int WK = 992;   // kc:  [W_ktk 864 | W_ptk 112 | W_mtk 16]
constexpr int WL = 560;   // ln:  [W_otl 384 | W_ptl 112 | W_ltl 64]
constexpr int SH = 1032;  // LDS act row stride in halves (516 dwords = 4 mod 32 -> free 2-way)

struct Params {
  const float *obs, *h, *in_orn_w, *in_orn_b, *W_oto, *W_lto, *W_otp, *W_ltp, *W_ptp,
              *W_otl, *W_ptl, *W_ltl, *W_ktk, *W_mtk, *W_ptk, *W_ktm,
              *b_orn, *b_pn, *b_ln, *b_kc, *b_mbon, *readout_w, *readout_b;
  __half *orn0, *orn1, *pn0, *pn1, *ln0, *ln1, *kc0, *kc1, *mbon;   // fp16 state
  __half *Wp_orn, *Wp_pn, *Wp_kc, *Wp_ln, *Wh_ktm, *Wh_ro;          // packed fp16 weights
  float *y, *h2;
  int *bar;
};

typedef _Float16 hv2 __attribute__((ext_vector_type(2)));

// ---- v_dot2_f32_f16: 2 fp16 MACs / instruction, f32 accumulate ----
__device__ __forceinline__ float fdot2u(unsigned w, unsigned a, float c) {
#if __has_builtin(__builtin_amdgcn_fdot2)
  return __builtin_amdgcn_fdot2(__builtin_bit_cast(hv2, w), __builtin_bit_cast(hv2, a), c, false);
#else
  __half2 hw = __builtin_bit_cast(__half2, w), ha = __builtin_bit_cast(__half2, a);
  c = fmaf(__low2float(hw), __low2float(ha), c);
  return fmaf(__high2float(hw), __high2float(ha), c);
#endif
}

// ---- fp32 ILP-4 dot (x_t path only) ----
template <int K>
__device__ __forceinline__ float dot4(const float* __restrict__ w, const float* __restrict__ a) {
  const float4* w4 = (const float4*)w;
  const float4* a4 = (const float4*)a;
  float x0 = 0.f, x1 = 0.f, x2 = 0.f, x3 = 0.f;
#pragma unroll 4
  for (int i = 0; i < K / 4; ++i) {
    float4 wv = w4[i], av = a4[i];
    x0 = fmaf(wv.x, av.x, x0); x1 = fmaf(wv.y, av.y, x1);
    x2 = fmaf(wv.z, av.z, x2); x3 = fmaf(wv.w, av.w, x3);
  }
  return (x0 + x1) + (x2 + x3);
}

// ---- single-output fp16 dot: 8 halves (1 uint4 each side) -> 4 fdot2 per iter ----
template <int K>  // K multiple of 8; both pointers 16B-aligned
__device__ __forceinline__ float doth2(const __half* __restrict__ w, const __half* __restrict__ a) {
  const uint4* w4 = (const uint4*)w;
  const uint4* a4 = (const uint4*)a;
  float x0 = 0.f, x1 = 0.f, x2 = 0.f, x3 = 0.f;
#pragma unroll 4
  for (int i = 0; i < K / 8; ++i) {
    uint4 wv = w4[i], av = a4[i];
    x0 = fdot2u(wv.x, av.x, x0); x1 = fdot2u(wv.y, av.y, x1);
    x2 = fdot2u(wv.z, av.z, x2); x3 = fdot2u(wv.w, av.w, x3);
  }
  return (x0 + x1) + (x2 + x3);
}

// ---- dual-output fp16 dot: one act read feeds two weight rows (halves LDS traffic) ----
template <int K>
__device__ __forceinline__ void ddoth2(const __half* __restrict__ w0, const __half* __restrict__ w1,
                                       const __half* __restrict__ a, float& r0, float& r1) {
  const uint4* W0 = (const uint4*)w0;
  const uint4* W1 = (const uint4*)w1;
  const uint4* A  = (const uint4*)a;
  float x0=0,x1=0,x2=0,x3=0, y0=0,y1=0,y2=0,y3=0;
#pragma unroll 4
  for (int i = 0; i < K / 8; ++i) {
    uint4 av = A[i], u = W0[i], v = W1[i];
    x0 = fdot2u(u.x, av.x, x0); x1 = fdot2u(u.y, av.y, x1);
    x2 = fdot2u(u.z, av.z, x2); x3 = fdot2u(u.w, av.w, x3);
    y0 = fdot2u(v.x, av.x, y0); y1 = fdot2u(v.y, av.y, y1);
    y2 = fdot2u(v.z, av.z, y2); y3 = fdot2u(v.w, av.w, y3);
  }
  r0 += (x0 + x1) + (x2 + x3);
  r1 += (y0 + y1) + (y2 + y3);
}

// ---- stage a [BT x widthH] fp16 state segment into LDS (uint4 = 8 halves/op) ----
__device__ __forceinline__ void load_seg_h(__half* dst, int offH,
                                           const __half* g, int widthH, int b0, int tid) {
  int w8 = widthH >> 3;
  const uint4* g4 = (const uint4*)(g + (size_t)b0 * widthH);
  for (int idx = tid; idx < BT * w8; idx += NTHREADS) {
    int b = idx / w8, k = idx - b * w8;
    *(uint4*)(dst + b * SH + offH + 8 * k) = g4[(size_t)b * w8 + k];
  }
}

// ---- agent-scope (LLC) store of a packed half2 (weight packing) ----
__device__ __forceinline__ void st_h2(__half* p, float v0, float v1) {
  __half2 h = __floats2half2_rn(v0, v1);
  __hip_atomic_store((unsigned*)p, __builtin_bit_cast(unsigned, h),
                     __ATOMIC_RELAXED, __HIP_MEMORY_SCOPE_AGENT);
}

// ---- 16-WG barrier (HW-validated: grid=256, 1 block/CU, bg = wg & 15, stride-16
//      members all on XCD bg&7). Flags: relaxed agent atomics (LLC). Data: XCD L2.
//      Release: vmcnt(0). Acquire: L1-only invalidate; L2 is never flushed. ----
__device__ __forceinline__ void bar_sync(int* cnt, int* gen, int& lg, int tid) {
  __syncthreads();
  if (tid == 0) {
    int target = ++lg;
    asm volatile("s_waitcnt vmcnt(0)" ::: "memory");   // our stores visible in L2
    int old = __hip_atomic_fetch_add(cnt, 1, __ATOMIC_RELAXED, __HIP_MEMORY_SCOPE_AGENT);
    if (old == 15) {
      __hip_atomic_store(cnt, 0, __ATOMIC_RELAXED, __HIP_MEMORY_SCOPE_AGENT);
      asm volatile("s_waitcnt vmcnt(0)" ::: "memory");
      __hip_atomic_fetch_add(gen, 1, __ATOMIC_RELAXED, __HIP_MEMORY_SCOPE_AGENT);
    } else {
      while (__hip_atomic_load(gen, __ATOMIC_RELAXED, __HIP_MEMORY_SCOPE_AGENT) < target)
        __builtin_amdgcn_s_sleep(1);
    }
    asm volatile("buffer_inv sc0\n\ts_waitcnt vmcnt(0)" ::: "memory");  // L1-only inv
  }
  __syncthreads();
}

__global__ void __launch_bounds__(NTHREADS, 4)
conn_kernel(Params P) {
  cg::grid_group grid = cg::this_grid();
  // LDS: 16*1032*2 = 33024 B acts + 1536 B xs. 1 block/CU, 16 waves/CU.
  __shared__ __align__(16) __half acth[BT * SH];
  __shared__ float xs[BT * 24];
  const int tid = threadIdx.x;
  const int wg = blockIdx.x;
  const int bg = wg & 15, ng = wg >> 4, b0 = bg * BT;   // validated mapping (round 2)
  int* cnt = P.bar + bg * 64;
  int* gen = P.bar + bg * 64 + 16;
  int lg = 0;

  // ---- init 1: pack ALL hot-loop weights to fp16 rows matching the act layout ----
  {
    const int gid = wg * NTHREADS + tid, gstr = 256 * NTHREADS;
    for (int idx = gid; idx < 384 * (WO / 2); idx += gstr) {   // orn rows
      int r = idx / (WO / 2), c = (idx - r * (WO / 2)) * 2;
      float v0, v1;
      if (c < 384) { v0 = P.W_oto[(size_t)r * 384 + c]; v1 = P.W_oto[(size_t)r * 384 + c + 1]; }
      else         { v0 = P.W_lto[(size_t)r * 64 + c - 384]; v1 = P.W_lto[(size_t)r * 64 + c - 383]; }
      st_h2(&P.Wp_orn[(size_t)r * WO + c], v0, v1);
    }
    for (int idx = gid; idx < 112 * (WP / 2); idx += gstr) {   // pn rows (+16 zero pad)
      int r = idx / (WP / 2), c = (idx - r * (WP / 2)) * 2;
      float v0, v1;
      if      (c < 384) { v0 = P.W_otp[(size_t)r * 384 + c];     v1 = P.W_otp[(size_t)r * 384 + c + 1]; }
      else if (c < 448) { v0 = P.W_ltp[(size_t)r * 64 + c - 384]; v1 = P.W_ltp[(size_t)r * 64 + c - 383]; }
      else if (c < 560) { v0 = P.W_ptp[(size_t)r * 112 + c - 448]; v1 = P.W_ptp[(size_t)r * 112 + c - 447]; }
      else              { v0 = 0.f; v1 = 0.f; }
      st_h2(&P.Wp_pn[(size_t)r * WP + c], v0, v1);
    }
    for (int idx = gid; idx < 864 * (WK / 2); idx += gstr) {   // kc rows
      int r = idx / (WK / 2), c = (idx - r * (WK / 2)) * 2;
      float v0, v1;
      if      (c < 864) { v0 = P.W_ktk[(size_t)r * 864 + c];      v1 = P.W_ktk[(size_t)r * 864 + c + 1]; }
      else if (c < 976) { v0 = P.W_ptk[(size_t)r * 112 + c - 864]; v1 = P.W_ptk[(size_t)r * 112 + c - 863]; }
      else              { v0 = P.W_mtk[(size_t)r * 16 + c - 976];  v1 = P.W_mtk[(size_t)r * 16 + c - 975]; }
      st_h2(&P.Wp_kc[(size_t)r * WK + c], v0, v1);
    }
    for (int idx = gid; idx < 64 * (WL / 2); idx += gstr) {    // ln rows
      int r = idx / (WL / 2), c = (idx - r * (WL / 2)) * 2;
      float v0, v1;
      if      (c < 384) { v0 = P.W_otl[(size_t)r * 384 + c];      v1 = P.W_otl[(size_t)r * 384 + c + 1]; }
      else if (c < 496) { v0 = P.W_ptl[(size_t)r * 112 + c - 384]; v1 = P.W_ptl[(size_t)r * 112 + c - 383]; }
      else              { v0 = P.W_ltl[(size_t)r * 64 + c - 496];  v1 = P.W_ltl[(size_t)r * 64 + c - 495]; }
      st_h2(&P.Wp_ln[(size_t)r * WL + c], v0, v1);
    }
    for (int idx = gid; idx < 16 * 432; idx += gstr) {         // W_ktm 16x864
      int c = idx * 2;
      st_h2(&P.Wh_ktm[c], P.W_ktm[c], P.W_ktm[c + 1]);
    }
    for (int idx = gid; idx < 1440 * 8; idx += gstr) {         // readout_w 1440x16
      int c = idx * 2;
      st_h2(&P.Wh_ro[c], P.readout_w[c], P.readout_w[c + 1]);
    }
  }

  // ---- init 2: scatter h into parity-1 fp16 state; init this bg's barrier ----
  if (ng == 0) {
    if (tid == 0) { *cnt = 0; *gen = 0; }
    for (int idx = tid; idx < BT * HID; idx += NTHREADS) {
      int b = idx / HID, pos = idx - b * HID, gb = b0 + b;
      __half v = __float2half(P.h[(size_t)gb * HID + pos]);
      if      (pos < 384)  P.orn1[(size_t)gb * ORN + pos] = v;
      else if (pos < 496)  P.pn1[gb * PN + (pos - 384)] = v;
      else if (pos < 560)  P.ln1[gb * LN + (pos - 496)] = v;
      else if (pos < 1424) P.kc1[(size_t)gb * KC + (pos - 560)] = v;
      else                 P.mbon[gb * MB + (pos - 1424)] = v;
    }
  }
  grid.sync();  // once: publishes packed weights + init + barrier zeros

  for (int s = 0; s < Tst * 4; ++s) {
    const int t = s >> 2, i = s & 3, p = s & 1;
    __half* ornN = p ? P.orn1 : P.orn0;  const __half* ornO = p ? P.orn0 : P.orn1;
    __half* pnN  = p ? P.pn1  : P.pn0;   const __half* pnO  = p ? P.pn0  : P.pn1;
    __half* lnN  = p ? P.ln1  : P.ln0;   const __half* lnO  = p ? P.ln0  : P.ln1;
    __half* kcN  = p ? P.kc1  : P.kc0;   const __half* kcO  = p ? P.kc0  : P.kc1;

    // ==== Stage A: orn j-blocked x2 (0-191) + mbon_{s-1} (192-255) + x_t (640+, i==0) ====
    load_seg_h(acth, 0,   ornO, ORN, b0, tid);
    load_seg_h(acth, 384, lnO,  LN,  b0, tid);
    if (i == 0 && tid >= 640) {  // x_t slice, once per timestep, overlaps staging
      for (int o = tid - 640; o < BT * 24; o += 384) {
        int b = o / 24, jl = o - b * 24, j = ng * 24 + jl;
        xs[b * 24 + jl] = P.in_orn_b[j]
          + dot4<OBS>(P.in_orn_w + (size_t)j * OBS,
                      P.obs + ((size_t)(b0 + b) * Tst + t) * OBS);
      }
    }
    __syncthreads();
    if (tid < 192) {  // 3 waves; 2 outputs/thread share one act stream
      int b = tid & 15, jp = tid >> 4;            // jp in [0,12)
      int j0 = ng * 24 + 2 * jp, j1 = j0 + 1;
      float r0 = xs[b * 24 + 2 * jp]     + P.b_orn[j0];
      float r1 = xs[b * 24 + 2 * jp + 1] + P.b_orn[j1];
      ddoth2<WO>(P.Wp_orn + (size_t)j0 * WO, P.Wp_orn + (size_t)j1 * WO,
                 acth + b * SH, r0, r1);
      *(__half2*)&ornN[(size_t)(b0 + b) * ORN + j0] = __floats2half2_rn(tanhf(r0), tanhf(r1));
    } else if (tid < 256 && s > 0) {  // mbon: wave 3, 4-way K-split over global kcO
      int idx = tid - 192, b = idx >> 2, ks = idx & 3;
      float part = doth2<216>(P.Wh_ktm + (size_t)ng * KC + ks * 216,
                              kcO + (size_t)(b0 + b) * KC + ks * 216);
      part += __shfl_xor(part, 1);
      part += __shfl_xor(part, 2);
      if (ks == 0)
        P.mbon[(b0 + b) * MB + ng] = __float2half(tanhf(part + P.b_mbon[ng]));
    }
    bar_sync(cnt, gen, lg, tid);

    // ==== Stage B: pn 4-way K-split (0-447, branchless) + y_{t-1} (512+, i==0) ====
    load_seg_h(acth, 0,   ornN, ORN, b0, tid);
    load_seg_h(acth, 384, lnO,  LN,  b0, tid);
    load_seg_h(acth, 448, pnO,  PN,  b0, tid);
    for (int idx = tid; idx < BT * 2; idx += NTHREADS) {  // zero pad [560..576)
      int b = idx >> 1, k = idx & 1;
      *(uint4*)(acth + b * SH + 560 + 8 * k) = make_uint4(0, 0, 0, 0);
    }
    __syncthreads();
    if (tid < 448) {  // 7 waves; ks = pointer offset, single code path
      int b = tid & 15, ks = (tid >> 4) & 3, j = tid >> 6, jg = ng * 7 + j;
      float r = doth2<144>(P.Wp_pn + (size_t)jg * WP + ks * 144,
                           acth + b * SH + ks * 144);
      r += __shfl_xor(r, 16);
      r += __shfl_xor(r, 32);
      if (ks == 0)
        pnN[(size_t)(b0 + b) * PN + jg] = __float2half(tanhf(r + P.b_pn[jg]));
    } else if (i == 0 && s > 0 && tid >= 512) {  // y_{t-1}: rank-16 readout from mbon
      for (int o = tid - 512; o < BT * 90; o += 512) {
        int b = o / 90, jl = o - b * 90, j = ng * 90 + jl;
        float yv = P.readout_b[j]
          + doth2<MB>(P.Wh_ro + (size_t)j * MB, P.mbon + (size_t)(b0 + b) * MB);
        P.y[((size_t)(b0 + b) * Tst + (t - 1)) * HID + j] = yv;
      }
    }
    bar_sync(cnt, gen, lg, tid);

    // ==== Stage C: kc j-blocked x2 (0-431) + ln one wave (448-511) ====
    load_seg_h(acth, 0,   kcO,    KC, b0, tid);
    load_seg_h(acth, 864, pnN,    PN, b0, tid);
    load_seg_h(acth, 976, P.mbon, MB, b0, tid);
    __syncthreads();
    if (tid < 432) {  // 6.75 waves; 2 outputs/thread share one 992-half act stream
      int b = tid & 15, jp = tid >> 4;            // jp in [0,27)
      int j0 = ng * 54 + 2 * jp, j1 = j0 + 1;
      float r0 = P.b_kc[j0], r1 = P.b_kc[j1];
      ddoth2<WK>(P.Wp_kc + (size_t)j0 * WK, P.Wp_kc + (size_t)j1 * WK,
                 acth + b * SH, r0, r1);
      *(__half2*)&kcN[(size_t)(b0 + b) * KC + j0] = __floats2half2_rn(tanhf(r0), tanhf(r1));
    } else if (tid >= 448 && tid < 512) {  // ln: one wave, full K
      int l = tid - 448, b = l & 15, j = l >> 4, jg = ng * 4 + j;
      const __half* row = P.Wp_ln + (size_t)jg * WL;
      float r = P.b_ln[jg]
        + doth2<384>(row,       ornN + (size_t)(b0 + b) * ORN)
        + doth2<112>(row + 384, acth + b * SH + 864)            // pn from staged LDS
        + doth2<64> (row + 496, lnO + (size_t)(b0 + b) * LN);
      lnN[(size_t)(b0 + b) * LN + jg] = __float2half(tanhf(r));
    }
    bar_sync(cnt, gen, lg, tid);
  }

  // ================= tail: mbon_{511}, y_{127}, h2 =================
  if (tid < 64) {
    int b = tid >> 2, ks = tid & 3;
    float part = doth2<216>(P.Wh_ktm + (size_t)ng * KC + ks * 216,
                            P.kc1 + (size_t)(b0 + b) * KC + ks * 216);
    part += __shfl_xor(part, 1);
    part += __shfl_xor(part, 2);
    if (ks == 0)
      P.mbon[(b0 + b) * MB + ng] = __float2half(tanhf(part + P.b_mbon[ng]));
  }
  bar_sync(cnt, gen, lg, tid);
  for (int o = tid; o < BT * 90; o += NTHREADS) {
    int b = o / 90, jl = o - b * 90, j = ng * 90 + jl;
    float acc = P.readout_b[j]
      + doth2<MB>(P.Wh_ro + (size_t)j * MB, P.mbon + (size_t)(b0 + b) * MB);
    P.y[((size_t)(b0 + b) * Tst + (Tst - 1)) * HID + j] = acc;
  }
  for (int idx = tid; idx < BT * 90; idx += NTHREADS) {
    int b = idx / 90, pos = idx - b * 90, gb = b0 + b;
    float v; int hp;
    if      (pos < 24) { v = __half2float(P.orn1[(size_t)gb * ORN + ng * 24 + pos]); hp = ng * 24 + pos; }
    else if (pos < 31) { int l = pos - 24; v = __half2float(P.pn1[gb * PN + ng * 7 + l]); hp = 384 + ng * 7 + l; }
    else if (pos < 35) { int l = pos - 31; v = __half2float(P.ln1[gb * LN + ng * 4 + l]); hp = 496 + ng * 4 + l; }
    else if (pos < 89) { int l = pos - 35; v = __half2float(P.kc1[(size_t)gb * KC + ng * 54 + l]); hp = 560 + ng * 54 + l; }
    else               { v = __half2float(P.mbon[gb * MB + ng]); hp = 1424 + ng; }
    P.h2[(size_t)gb * HID + hp] = v;
  }
}

extern "C" void kernel_launch(void* const* d_in, const int* in_sizes, int n_in,
                              void* d_out, int out_size, void* d_ws, size_t ws_size,
                              hipStream_t stream) {
  Params P;
  P.obs       = (const float*)d_in[0];
  P.h         = (const float*)d_in[1];
  P.in_orn_w  = (const float*)d_in[2];
  P.in_orn_b  = (const float*)d_in[3];
  P.W_oto     = (const float*)d_in[4];
  P.W_lto     = (const float*)d_in[5];
  P.W_otp     = (const float*)d_in[6];
  P.W_ltp     = (const float*)d_in[7];
  P.W_ptp     = (const float*)d_in[8];
  P.W_otl     = (const float*)d_in[9];
  P.W_ptl     = (const float*)d_in[10];
  P.W_ltl     = (const float*)d_in[11];
  P.W_ktk     = (const float*)d_in[12];
  P.W_mtk     = (const float*)d_in[13];
  P.W_ptk     = (const float*)d_in[14];
  P.W_ktm     = (const float*)d_in[15];
  P.b_orn     = (const float*)d_in[16];
  P.b_pn      = (const float*)d_in[17];
  P.b_ln      = (const float*)d_in[18];
  P.b_kc      = (const float*)d_in[19];
  P.b_mbon    = (const float*)d_in[20];
  P.readout_w = (const float*)d_in[21];
  P.readout_b = (const float*)d_in[22];

  __half* wh = (__half*)d_ws;
  size_t off = 0;   // all region sizes are multiples of 8 halves -> 16B alignment kept
  P.orn0 = wh + off; off += (size_t)Bsz * ORN;
  P.orn1 = wh + off; off += (size_t)Bsz * ORN;
  P.pn0  = wh + off; off += (size_t)Bsz * PN;
  P.pn1  = wh + off; off += (size_t)Bsz * PN;
  P.ln0  = wh + off; off += (size_t)Bsz * LN;
  P.ln1  = wh + off; off += (size_t)Bsz * LN;
  P.kc0  = wh + off; off += (size_t)Bsz * KC;
  P.kc1  = wh + off; off += (size_t)Bsz * KC;
  P.mbon = wh + off; off += (size_t)Bsz * MB;
  P.bar  = (int*)(wh + off); off += 16 * 64 * 2;  // 16 bg x 64 ints
  P.Wp_orn = wh + off; off += (size_t)384 * WO;
  P.Wp_pn  = wh + off; off += (size_t)112 * WP;
  P.Wp_kc  = wh + off; off += (size_t)864 * WK;
  P.Wp_ln  = wh + off; off += (size_t)64  * WL;
  P.Wh_ktm = wh + off; off += (size_t)16  * KC;
  P.Wh_ro  = wh + off; off += (size_t)HID * MB;

  P.y  = (float*)d_out;
  P.h2 = (float*)d_out + (size_t)Bsz * Tst * HID;

  void* args[] = { &P };
  hipLaunchCooperativeKernel((void*)conn_kernel, dim3(256), dim3(NTHREADS), args, 0, stream);
}

// Round 8
// 16408.427 us; speedup vs baseline: 3.2458x; 1.0249x over previous
//
#include <hip/hip_runtime.h>
#include <hip/hip_fp16.h>
#include <hip/hip_cooperative_groups.h>

namespace cg = cooperative_groups;

#define NTHREADS 1024
#define BT 16   // batch tile per workgroup group

constexpr int Bsz = 256, Tst = 128, HID = 1440;
constexpr int ORN = 384, PN = 112, LN = 64, KC = 864, MB = 16, OBS = 64;
// packed fp16 row widths (match LDS act layout exactly)
constexpr int WO = 448;   // orn: [W_oto 384 | W_lto 64]
constexpr int WP = 576;   // pn:  [W_otp 384 | W_ltp 64 | W_ptp 112 | zero 16]
constexpr int WK = 992;   // kc:  [W_ktk 864 | W_ptk 112 | W_mtk 16]
constexpr int WL = 560;   // ln:  [W_otl 384 | W_ptl 112 | W_ltl 64]
constexpr int SH = 1320;  // LDS act row stride in halves (660 dw = 20 mod 32 -> free 2-way)
// LDS act layout: stage A: [kcO 0..864 | ornO 864..1248 | lnO 1248..1312]
//                 stage B: [ornN 0..384 | lnO 384..448 | pnO 448..560 | zero..576]
//                 stage C: [+ pnN 576..688 | mbon 688..704]  (B's 0..448 stays live for ln)

struct Params {
  const float *obs, *h, *in_orn_w, *in_orn_b, *W_oto, *W_lto, *W_otp, *W_ltp, *W_ptp,
              *W_otl, *W_ptl, *W_ltl, *W_ktk, *W_mtk, *W_ptk, *W_ktm,
              *b_orn, *b_pn, *b_ln, *b_kc, *b_mbon, *readout_w, *readout_b;
  __half *orn0, *orn1, *pn0, *pn1, *ln0, *ln1, *kc0, *kc1, *mbon;   // fp16 state
  __half *Wp_orn, *Wp_pn, *Wp_kc, *Wp_ln, *Wh_ktm, *Wh_ro;          // packed fp16 weights
  float *y, *h2;
  int *bar;
};

typedef _Float16 hv2 __attribute__((ext_vector_type(2)));

// ---- v_dot2_f32_f16: 2 fp16 MACs / instruction, f32 accumulate ----
__device__ __forceinline__ float fdot2u(unsigned w, unsigned a, float c) {
#if __has_builtin(__builtin_amdgcn_fdot2)
  return __builtin_amdgcn_fdot2(__builtin_bit_cast(hv2, w), __builtin_bit_cast(hv2, a), c, false);
#else
  __half2 hw = __builtin_bit_cast(__half2, w), ha = __builtin_bit_cast(__half2, a);
  c = fmaf(__low2float(hw), __low2float(ha), c);
  return fmaf(__high2float(hw), __high2float(ha), c);
#endif
}

// ---- fp32 ILP-4 dot (x_t path only) ----
template <int K>
__device__ __forceinline__ float dot4(const float* __restrict__ w, const float* __restrict__ a) {
  const float4* w4 = (const float4*)w;
  const float4* a4 = (const float4*)a;
  float x0 = 0.f, x1 = 0.f, x2 = 0.f, x3 = 0.f;
#pragma unroll 4
  for (int i = 0; i < K / 4; ++i) {
    float4 wv = w4[i], av = a4[i];
    x0 = fmaf(wv.x, av.x, x0); x1 = fmaf(wv.y, av.y, x1);
    x2 = fmaf(wv.z, av.z, x2); x3 = fmaf(wv.w, av.w, x3);
  }
  return (x0 + x1) + (x2 + x3);
}

// ---- single-output fp16 dot: 8 halves (1 uint4 each side) -> 4 fdot2 per iter ----
template <int K>  // K multiple of 8; both pointers 16B-aligned
__device__ __forceinline__ float doth2(const __half* __restrict__ w, const __half* __restrict__ a) {
  const uint4* w4 = (const uint4*)w;
  const uint4* a4 = (const uint4*)a;
  float x0 = 0.f, x1 = 0.f, x2 = 0.f, x3 = 0.f;
#pragma unroll 4
  for (int i = 0; i < K / 8; ++i) {
    uint4 wv = w4[i], av = a4[i];
    x0 = fdot2u(wv.x, av.x, x0); x1 = fdot2u(wv.y, av.y, x1);
    x2 = fdot2u(wv.z, av.z, x2); x3 = fdot2u(wv.w, av.w, x3);
  }
  return (x0 + x1) + (x2 + x3);
}

// ---- dual-output fp16 dot: one act read feeds two weight rows; unroll 8 for MLP ----
template <int K>
__device__ __forceinline__ void ddoth2(const __half* __restrict__ w0, const __half* __restrict__ w1,
                                       const __half* __restrict__ a, float& r0, float& r1) {
  const uint4* W0 = (const uint4*)w0;
  const uint4* W1 = (const uint4*)w1;
  const uint4* A  = (const uint4*)a;
  float x0=0,x1=0,x2=0,x3=0, y0=0,y1=0,y2=0,y3=0;
#pragma unroll 8
  for (int i = 0; i < K / 8; ++i) {
    uint4 av = A[i], u = W0[i], v = W1[i];
    x0 = fdot2u(u.x, av.x, x0); x1 = fdot2u(u.y, av.y, x1);
    x2 = fdot2u(u.z, av.z, x2); x3 = fdot2u(u.w, av.w, x3);
    y0 = fdot2u(v.x, av.x, y0); y1 = fdot2u(v.y, av.y, y1);
    y2 = fdot2u(v.z, av.z, y2); y3 = fdot2u(v.w, av.w, y3);
  }
  r0 += (x0 + x1) + (x2 + x3);
  r1 += (y0 + y1) + (y2 + y3);
}

// ---- stage a [BT x widthH] fp16 state segment into LDS (uint4 = 8 halves/op) ----
__device__ __forceinline__ void load_seg_h(__half* dst, int offH,
                                           const __half* g, int widthH, int b0, int tid) {
  int w8 = widthH >> 3;
  const uint4* g4 = (const uint4*)(g + (size_t)b0 * widthH);
  for (int idx = tid; idx < BT * w8; idx += NTHREADS) {
    int b = idx / w8, k = idx - b * w8;
    *(uint4*)(dst + b * SH + offH + 8 * k) = g4[(size_t)b * w8 + k];
  }
}

// ---- agent-scope (LLC) store of a packed half2 (weight packing) ----
__device__ __forceinline__ void st_h2(__half* p, float v0, float v1) {
  __half2 h = __floats2half2_rn(v0, v1);
  __hip_atomic_store((unsigned*)p, __builtin_bit_cast(unsigned, h),
                     __ATOMIC_RELAXED, __HIP_MEMORY_SCOPE_AGENT);
}

// ---- 16-WG barrier (HW-validated: grid=256, 1 block/CU, bg = wg & 15, stride-16
//      members all on XCD bg&7). Flags: relaxed agent atomics (LLC). Data: XCD L2.
//      Release: vmcnt(0). Acquire: L1-only invalidate; L2 is never flushed. ----
__device__ __forceinline__ void bar_sync(int* cnt, int* gen, int& lg, int tid) {
  __syncthreads();
  if (tid == 0) {
    int target = ++lg;
    asm volatile("s_waitcnt vmcnt(0)" ::: "memory");   // our stores visible in L2
    int old = __hip_atomic_fetch_add(cnt, 1, __ATOMIC_RELAXED, __HIP_MEMORY_SCOPE_AGENT);
    if (old == 15) {
      __hip_atomic_store(cnt, 0, __ATOMIC_RELAXED, __HIP_MEMORY_SCOPE_AGENT);
      asm volatile("s_waitcnt vmcnt(0)" ::: "memory");
      __hip_atomic_fetch_add(gen, 1, __ATOMIC_RELAXED, __HIP_MEMORY_SCOPE_AGENT);
    } else {
      while (__hip_atomic_load(gen, __ATOMIC_RELAXED, __HIP_MEMORY_SCOPE_AGENT) < target)
        __builtin_amdgcn_s_sleep(1);
    }
    asm volatile("buffer_inv sc0\n\ts_waitcnt vmcnt(0)" ::: "memory");  // L1-only inv
  }
  __syncthreads();
}

__global__ void __launch_bounds__(NTHREADS, 4)
conn_kernel(Params P) {
  cg::grid_group grid = cg::this_grid();
  // LDS: 16*1320*2 = 42240 B acts + 1536 B xs. 1 block/CU, 16 waves/CU.
  __shared__ __align__(16) __half acth[BT * SH];
  __shared__ float xs[BT * 24];
  const int tid = threadIdx.x;
  const int wg = blockIdx.x;
  const int bg = wg & 15, ng = wg >> 4, b0 = bg * BT;   // validated mapping (round 2)
  int* cnt = P.bar + bg * 64;
  int* gen = P.bar + bg * 64 + 16;
  int lg = 0;

  // ---- init 1: pack ALL hot-loop weights to fp16 rows matching the act layout ----
  {
    const int gid = wg * NTHREADS + tid, gstr = 256 * NTHREADS;
    for (int idx = gid; idx < 384 * (WO / 2); idx += gstr) {   // orn rows
      int r = idx / (WO / 2), c = (idx - r * (WO / 2)) * 2;
      float v0, v1;
      if (c < 384) { v0 = P.W_oto[(size_t)r * 384 + c]; v1 = P.W_oto[(size_t)r * 384 + c + 1]; }
      else         { v0 = P.W_lto[(size_t)r * 64 + c - 384]; v1 = P.W_lto[(size_t)r * 64 + c - 383]; }
      st_h2(&P.Wp_orn[(size_t)r * WO + c], v0, v1);
    }
    for (int idx = gid; idx < 112 * (WP / 2); idx += gstr) {   // pn rows (+16 zero pad)
      int r = idx / (WP / 2), c = (idx - r * (WP / 2)) * 2;
      float v0, v1;
      if      (c < 384) { v0 = P.W_otp[(size_t)r * 384 + c];     v1 = P.W_otp[(size_t)r * 384 + c + 1]; }
      else if (c < 448) { v0 = P.W_ltp[(size_t)r * 64 + c - 384]; v1 = P.W_ltp[(size_t)r * 64 + c - 383]; }
      else if (c < 560) { v0 = P.W_ptp[(size_t)r * 112 + c - 448]; v1 = P.W_ptp[(size_t)r * 112 + c - 447]; }
      else              { v0 = 0.f; v1 = 0.f; }
      st_h2(&P.Wp_pn[(size_t)r * WP + c], v0, v1);
    }
    for (int idx = gid; idx < 864 * (WK / 2); idx += gstr) {   // kc rows
      int r = idx / (WK / 2), c = (idx - r * (WK / 2)) * 2;
      float v0, v1;
      if      (c < 864) { v0 = P.W_ktk[(size_t)r * 864 + c];      v1 = P.W_ktk[(size_t)r * 864 + c + 1]; }
      else if (c < 976) { v0 = P.W_ptk[(size_t)r * 112 + c - 864]; v1 = P.W_ptk[(size_t)r * 112 + c - 863]; }
      else              { v0 = P.W_mtk[(size_t)r * 16 + c - 976];  v1 = P.W_mtk[(size_t)r * 16 + c - 975]; }
      st_h2(&P.Wp_kc[(size_t)r * WK + c], v0, v1);
    }
    for (int idx = gid; idx < 64 * (WL / 2); idx += gstr) {    // ln rows
      int r = idx / (WL / 2), c = (idx - r * (WL / 2)) * 2;
      float v0, v1;
      if      (c < 384) { v0 = P.W_otl[(size_t)r * 384 + c];      v1 = P.W_otl[(size_t)r * 384 + c + 1]; }
      else if (c < 496) { v0 = P.W_ptl[(size_t)r * 112 + c - 384]; v1 = P.W_ptl[(size_t)r * 112 + c - 383]; }
      else              { v0 = P.W_ltl[(size_t)r * 64 + c - 496];  v1 = P.W_ltl[(size_t)r * 64 + c - 495]; }
      st_h2(&P.Wp_ln[(size_t)r * WL + c], v0, v1);
    }
    for (int idx = gid; idx < 16 * 432; idx += gstr) {         // W_ktm 16x864
      int c = idx * 2;
      st_h2(&P.Wh_ktm[c], P.W_ktm[c], P.W_ktm[c + 1]);
    }
    for (int idx = gid; idx < 1440 * 8; idx += gstr) {         // readout_w 1440x16
      int c = idx * 2;
      st_h2(&P.Wh_ro[c], P.readout_w[c], P.readout_w[c + 1]);
    }
  }

  // ---- init 2: scatter h into parity-1 fp16 state; init this bg's barrier ----
  if (ng == 0) {
    if (tid == 0) { *cnt = 0; *gen = 0; }
    for (int idx = tid; idx < BT * HID; idx += NTHREADS) {
      int b = idx / HID, pos = idx - b * HID, gb = b0 + b;
      __half v = __float2half(P.h[(size_t)gb * HID + pos]);
      if      (pos < 384)  P.orn1[(size_t)gb * ORN + pos] = v;
      else if (pos < 496)  P.pn1[gb * PN + (pos - 384)] = v;
      else if (pos < 560)  P.ln1[gb * LN + (pos - 496)] = v;
      else if (pos < 1424) P.kc1[(size_t)gb * KC + (pos - 560)] = v;
      else                 P.mbon[gb * MB + (pos - 1424)] = v;
    }
  }
  grid.sync();  // once: publishes packed weights + init + barrier zeros

  for (int s = 0; s < Tst * 4; ++s) {
    const int t = s >> 2, i = s & 3, p = s & 1;
    __half* ornN = p ? P.orn1 : P.orn0;  const __half* ornO = p ? P.orn0 : P.orn1;
    __half* pnN  = p ? P.pn1  : P.pn0;   const __half* pnO  = p ? P.pn0  : P.pn1;
    __half* lnN  = p ? P.ln1  : P.ln0;   const __half* lnO  = p ? P.ln0  : P.ln1;
    __half* kcN  = p ? P.kc1  : P.kc0;   const __half* kcO  = p ? P.kc0  : P.kc1;

    float kcp0 = 0.f, kcp1 = 0.f;   // kc partial accumulators, live across stages

    // ==== Stage A: kc 864-K partial (0-431) + orn (432-623) + mbon_{s-1} (624-687)
    //      + x_t (688-1023, i==0).  ~11 of 16 waves computing. ====
    load_seg_h(acth, 0,    kcO,  KC,  b0, tid);
    load_seg_h(acth, 864,  ornO, ORN, b0, tid);
    load_seg_h(acth, 1248, lnO,  LN,  b0, tid);
    if (i == 0 && tid >= 688) {  // x_t slice, once per timestep, overlaps staging
      for (int o = tid - 688; o < BT * 24; o += 336) {
        int b = o / 24, jl = o - b * 24, j = ng * 24 + jl;
        xs[b * 24 + jl] = P.in_orn_b[j]
          + dot4<OBS>(P.in_orn_w + (size_t)j * OBS,
                      P.obs + ((size_t)(b0 + b) * Tst + t) * OBS);
      }
    }
    __syncthreads();
    if (tid < 432) {  // kc partial: W_ktk . kc_old (864 of 992 K), result stays in VGPRs
      int b = tid & 15, jp = tid >> 4;            // jp in [0,27)
      int j0 = ng * 54 + 2 * jp, j1 = j0 + 1;
      kcp0 = P.b_kc[j0]; kcp1 = P.b_kc[j1];
      ddoth2<864>(P.Wp_kc + (size_t)j0 * WK, P.Wp_kc + (size_t)j1 * WK,
                  acth + b * SH, kcp0, kcp1);
    } else if (tid < 624) {  // orn: 2 outputs/thread share one act stream
      int l = tid - 432, b = l & 15, jp = l >> 4;  // jp in [0,12)
      int j0 = ng * 24 + 2 * jp, j1 = j0 + 1;
      float r0 = xs[b * 24 + 2 * jp]     + P.b_orn[j0];
      float r1 = xs[b * 24 + 2 * jp + 1] + P.b_orn[j1];
      ddoth2<WO>(P.Wp_orn + (size_t)j0 * WO, P.Wp_orn + (size_t)j1 * WO,
                 acth + b * SH + 864, r0, r1);
      *(__half2*)&ornN[(size_t)(b0 + b) * ORN + j0] = __floats2half2_rn(tanhf(r0), tanhf(r1));
    } else if (tid < 688 && s > 0) {  // mbon_{s-1}: kc_old from LDS, 4-way K-split
      int idx = tid - 624, b = idx >> 2, ks = idx & 3;
      float part = doth2<216>(P.Wh_ktm + (size_t)ng * KC + ks * 216,
                              acth + b * SH + ks * 216);
      part += __shfl_xor(part, 1);
      part += __shfl_xor(part, 2);
      if (ks == 0)
        P.mbon[(b0 + b) * MB + ng] = __float2half(tanhf(part + P.b_mbon[ng]));
    }
    bar_sync(cnt, gen, lg, tid);

    // ==== Stage B: pn 4-way K-split (0-447, branchless) + y_{t-1} (512+, i==0) ====
    load_seg_h(acth, 0,   ornN, ORN, b0, tid);
    load_seg_h(acth, 384, lnO,  LN,  b0, tid);
    load_seg_h(acth, 448, pnO,  PN,  b0, tid);
    for (int idx = tid; idx < BT * 2; idx += NTHREADS) {  // zero pad [560..576)
      int b = idx >> 1, k = idx & 1;
      *(uint4*)(acth + b * SH + 560 + 8 * k) = make_uint4(0, 0, 0, 0);
    }
    __syncthreads();
    if (tid < 448) {  // 7 waves; ks = pointer offset, single code path
      int b = tid & 15, ks = (tid >> 4) & 3, j = tid >> 6, jg = ng * 7 + j;
      float r = doth2<144>(P.Wp_pn + (size_t)jg * WP + ks * 144,
                           acth + b * SH + ks * 144);
      r += __shfl_xor(r, 16);
      r += __shfl_xor(r, 32);
      if (ks == 0)
        pnN[(size_t)(b0 + b) * PN + jg] = __float2half(tanhf(r + P.b_pn[jg]));
    } else if (i == 0 && s > 0 && tid >= 512) {  // y_{t-1}: rank-16 readout from mbon
      for (int o = tid - 512; o < BT * 90; o += 512) {
        int b = o / 90, jl = o - b * 90, j = ng * 90 + jl;
        float yv = P.readout_b[j]
          + doth2<MB>(P.Wh_ro + (size_t)j * MB, P.mbon + (size_t)(b0 + b) * MB);
        P.y[((size_t)(b0 + b) * Tst + (t - 1)) * HID + j] = yv;
      }
    }
    bar_sync(cnt, gen, lg, tid);

    // ==== Stage C: kc finish 128-K (0-431) + ln fully-LDS (448-511) ====
    load_seg_h(acth, 576, pnN,    PN, b0, tid);
    load_seg_h(acth, 688, P.mbon, MB, b0, tid);
    __syncthreads();
    if (tid < 432) {  // add W_ptk.pnN + W_mtk.mbon (contiguous [pnN|mbon] @ 576)
      int b = tid & 15, jp = tid >> 4;
      int j0 = ng * 54 + 2 * jp, j1 = j0 + 1;
      ddoth2<128>(P.Wp_kc + (size_t)j0 * WK + 864, P.Wp_kc + (size_t)j1 * WK + 864,
                  acth + b * SH + 576, kcp0, kcp1);
      *(__half2*)&kcN[(size_t)(b0 + b) * KC + j0] = __floats2half2_rn(tanhf(kcp0), tanhf(kcp1));
    } else if (tid >= 448 && tid < 512) {  // ln: one wave; all operands in LDS
      int l = tid - 448, b = l & 15, j = l >> 4, jg = ng * 4 + j;
      const __half* row = P.Wp_ln + (size_t)jg * WL;
      float r = P.b_ln[jg]
        + doth2<384>(row,       acth + b * SH)          // ornN staged in B
        + doth2<112>(row + 384, acth + b * SH + 576)    // pnN staged in C
        + doth2<64> (row + 496, acth + b * SH + 384);   // lnO staged in B
      lnN[(size_t)(b0 + b) * LN + jg] = __float2half(tanhf(r));
    }
    bar_sync(cnt, gen, lg, tid);
  }

  // ================= tail: mbon_{511}, y_{127}, h2 =================
  if (tid < 64) {
    int b = tid >> 2, ks = tid & 3;
    float part = doth2<216>(P.Wh_ktm + (size_t)ng * KC + ks * 216,
                            P.kc1 + (size_t)(b0 + b) * KC + ks * 216);
    part += __shfl_xor(part, 1);
    part += __shfl_xor(part, 2);
    if (ks == 0)
      P.mbon[(b0 + b) * MB + ng] = __float2half(tanhf(part + P.b_mbon[ng]));
  }
  bar_sync(cnt, gen, lg, tid);
  for (int o = tid; o < BT * 90; o += NTHREADS) {
    int b = o / 90, jl = o - b * 90, j = ng * 90 + jl;
    float acc = P.readout_b[j]
      + doth2<MB>(P.Wh_ro + (size_t)j * MB, P.mbon + (size_t)(b0 + b) * MB);
    P.y[((size_t)(b0 + b) * Tst + (Tst - 1)) * HID + j] = acc;
  }
  for (int idx = tid; idx < BT * 90; idx += NTHREADS) {
    int b = idx / 90, pos = idx - b * 90, gb = b0 + b;
    float v; int hp;
    if      (pos < 24) { v = __half2float(P.orn1[(size_t)gb * ORN + ng * 24 + pos]); hp = ng * 24 + pos; }
    else if (pos < 31) { int l = pos - 24; v = __half2float(P.pn1[gb * PN + ng * 7 + l]); hp = 384 + ng * 7 + l; }
    else if (pos < 35) { int l = pos - 31; v = __half2float(P.ln1[gb * LN + ng * 4 + l]); hp = 496 + ng * 4 + l; }
    else if (pos < 89) { int l = pos - 35; v = __half2float(P.kc1[(size_t)gb * KC + ng * 54 + l]); hp = 560 + ng * 54 + l; }
    else               { v = __half2float(P.mbon[gb * MB + ng]); hp = 1424 + ng; }
    P.h2[(size_t)gb * HID + hp] = v;
  }
}

extern "C" void kernel_launch(void* const* d_in, const int* in_sizes, int n_in,
                              void* d_out, int out_size, void* d_ws, size_t ws_size,
                              hipStream_t stream) {
  Params P;
  P.obs       = (const float*)d_in[0];
  P.h         = (const float*)d_in[1];
  P.in_orn_w  = (const float*)d_in[2];
  P.in_orn_b  = (const float*)d_in[3];
  P.W_oto     = (const float*)d_in[4];
  P.W_lto     = (const float*)d_in[5];
  P.W_otp     = (const float*)d_in[6];
  P.W_ltp     = (const float*)d_in[7];
  P.W_ptp     = (const float*)d_in[8];
  P.W_otl     = (const float*)d_in[9];
  P.W_ptl     = (const float*)d_in[10];
  P.W_ltl     = (const float*)d_in[11];
  P.W_ktk     = (const float*)d_in[12];
  P.W_mtk     = (const float*)d_in[13];
  P.W_ptk     = (const float*)d_in[14];
  P.W_ktm     = (const float*)d_in[15];
  P.b_orn     = (const float*)d_in[16];
  P.b_pn      = (const float*)d_in[17];
  P.b_ln      = (const float*)d_in[18];
  P.b_kc      = (const float*)d_in[19];
  P.b_mbon    = (const float*)d_in[20];
  P.readout_w = (const float*)d_in[21];
  P.readout_b = (const float*)d_in[22];

  __half* wh = (__half*)d_ws;
  size_t off = 0;   // all region sizes are multiples of 8 halves -> 16B alignment kept
  P.orn0 = wh + off; off += (size_t)Bsz * ORN;
  P.orn1 = wh + off; off += (size_t)Bsz * ORN;
  P.pn0  = wh + off; off += (size_t)Bsz * PN;
  P.pn1  = wh + off; off += (size_t)Bsz * PN;
  P.ln0  = wh + off; off += (size_t)Bsz * LN;
  P.ln1  = wh + off; off += (size_t)Bsz * LN;
  P.kc0  = wh + off; off += (size_t)Bsz * KC;
  P.kc1  = wh + off; off += (size_t)Bsz * KC;
  P.mbon = wh + off; off += (size_t)Bsz * MB;
  P.bar  = (int*)(wh + off); off += 16 * 64 * 2;  // 16 bg x 64 ints
  P.Wp_orn = wh + off; off += (size_t)384 * WO;
  P.Wp_pn  = wh + off; off += (size_t)112 * WP;
  P.Wp_kc  = wh + off; off += (size_t)864 * WK;
  P.Wp_ln  = wh + off; off += (size_t)64  * WL;
  P.Wh_ktm = wh + off; off += (size_t)16  * KC;
  P.Wh_ro  = wh + off; off += (size_t)HID * MB;

  P.y  = (float*)d_out;
  P.h2 = (float*)d_out + (size_t)Bsz * Tst * HID;

  void* args[] = { &P };
  hipLaunchCooperativeKernel((void*)conn_kernel, dim3(256), dim3(NTHREADS), args, 0, stream);
}